// Round 3
// baseline (1023.946 us; speedup 1.0000x reference)
//
#include <hip/hip_runtime.h>

typedef unsigned short u16;
typedef unsigned int u32;

#define DIM 64
#define NGRAPH 320
#define NPG 200
#define EPG 3200
#define NSTEPS 5
#define NITERS 6
#define NTILES 13  // ceil(200/16)
#define NPAD 208   // NTILES*16

typedef __attribute__((ext_vector_type(8))) short bf16x8;
typedef __attribute__((ext_vector_type(4))) float f32x4;

__device__ __forceinline__ float bf2f(u16 u) {
  u32 x = ((u32)u) << 16;
  float f;
  __builtin_memcpy(&f, &x, 4);
  return f;
}
__device__ __forceinline__ u16 f2bf(float f) {
  u32 x;
  __builtin_memcpy(&x, &f, 4);
  x = (x + 0x7FFFu + ((x >> 16) & 1u)) >> 16;
  return (u16)x;
}
__device__ __forceinline__ float bflo(u32 w) {
  u32 x = w << 16;
  float f;
  __builtin_memcpy(&f, &x, 4);
  return f;
}
__device__ __forceinline__ float bfhi(u32 w) {
  u32 x = w & 0xffff0000u;
  float f;
  __builtin_memcpy(&f, &x, 4);
  return f;
}
__device__ __forceinline__ float sigmf(float x) { return 1.0f / (1.0f + __expf(-x)); }
// XOR swizzle for bf16 [row][64] LDS tiles read as ds_read_b128 at 128B row stride:
// flips u16-index bits 3..5 by row&7 -> 16B chunks stay contiguous, banks spread.
__device__ __forceinline__ int swz(int row, int col) { return row * 64 + (col ^ ((row & 7) << 3)); }

// ---------------- prep ----------------

// 3-phase CSR: phase p = etype>>1, local t = etype&1. rec = t*NPG + src (direct wh row id).
__global__ void __launch_bounds__(256) k_csr(const int* __restrict__ src,
                                             const int* __restrict__ dst,
                                             const int* __restrict__ ety,
                                             u16* __restrict__ recs,
                                             int* __restrict__ rows) {
  __shared__ int cnt[3 * NPG];
  __shared__ int rofs[3 * (NPG + 1)];
  int g = blockIdx.x, tid = threadIdx.x;
  int base = g * NPG;
  for (int i = tid; i < 3 * NPG; i += 256) cnt[i] = 0;
  __syncthreads();
  for (int e = tid; e < EPG; e += 256) {
    int d = dst[g * EPG + e] - base;
    int t = ety[g * EPG + e];
    atomicAdd(&cnt[(t >> 1) * NPG + d], 1);
  }
  __syncthreads();
  if (tid == 0) {
    int s = 0;
    for (int p = 0; p < 3; p++) {
      for (int n = 0; n < NPG; n++) {
        rofs[p * (NPG + 1) + n] = s;
        s += cnt[p * NPG + n];
      }
      rofs[p * (NPG + 1) + NPG] = s;
    }
  }
  __syncthreads();
  for (int i = tid; i < 3 * NPG; i += 256) cnt[i] = rofs[(i / NPG) * (NPG + 1) + (i % NPG)];
  __syncthreads();
  for (int e = tid; e < EPG; e += 256) {
    int d = dst[g * EPG + e] - base;
    int t = ety[g * EPG + e];
    int sl = src[g * EPG + e] - base;
    int pos = atomicAdd(&cnt[(t >> 1) * NPG + d], 1);
    recs[g * EPG + pos] = (u16)((t & 1) * NPG + sl);
  }
  for (int i = tid; i < 3 * (NPG + 1); i += 256) rows[g * 3 * (NPG + 1) + i] = rofs[i];
}

// All weight conversions/transposes in ONE launch (163840 elems = 640 x 256).
__global__ void __launch_bounds__(256) k_prep(
    const float* __restrict__ W_edge, const float* __restrict__ gWih, const float* __restrict__ gWhh,
    const float* __restrict__ lWi0, const float* __restrict__ lWh0,
    const float* __restrict__ lWi1, const float* __restrict__ lWh1,
    const float* __restrict__ lWi2, const float* __restrict__ lWh2,
    u16* __restrict__ WeTb, u16* __restrict__ Wihb, u16* __restrict__ Whhb,
    u16* __restrict__ WTih0b, u16* __restrict__ WThh0b,
    u16* __restrict__ WTih1b, u16* __restrict__ WThh1b,
    u16* __restrict__ WTih2b, u16* __restrict__ WThh2b) {
  int i = blockIdx.x * 256 + threadIdx.x;
  if (i < 24576) {  // WeT: [t][o][k] <- W_edge[t][k][o]
    int t = i >> 12, rem = i & 4095, o = rem >> 6, k = rem & 63;
    WeTb[i] = f2bf(W_edge[t * 4096 + k * 64 + o]);
  } else if (i < 36864) {
    int idx = i - 24576;
    Wihb[idx] = f2bf(gWih[idx]);
  } else if (i < 49152) {
    int idx = i - 36864;
    Whhb[idx] = f2bf(gWhh[idx]);
  } else if (i < 81920) {  // WTih0: [k<128][j<256] <- lWi0[j][k]
    int idx = i - 49152;
    int k = idx >> 8, jj = idx & 255;
    WTih0b[idx] = f2bf(lWi0[jj * 128 + k]);
  } else {  // five [k<64][j<256] transposes
    int idx = i - 81920;
    int seg = idx >> 14;
    int r = idx & 16383;
    int k = r >> 8, jj = r & 255;
    const float* sp = seg == 0 ? lWh0 : seg == 1 ? lWi1 : seg == 2 ? lWh1 : seg == 3 ? lWi2 : lWh2;
    u16* dp = seg == 0 ? WThh0b : seg == 1 ? WTih1b : seg == 2 ? WThh1b : seg == 3 ? WTih2b : WThh2b;
    dp[r] = f2bf(sp[jj * 64 + k]);
  }
}

// ---------------- fully fused GGNN + Set2Set: one block = one graph ----------------
// __launch_bounds__(512, 1): min-waves/EU = 1 relaxes the allocator's default
// occupancy target (which pinned VGPR=128 and spilled ~165MB to scratch, R1/R2).
// Flat WG size 512 still caps allocation at 256 VGPR (2 waves/SIMD schedulable).

__global__ void __launch_bounds__(512, 1) k_ggnn(
    const float* __restrict__ feats,
    const u16* __restrict__ WeTb, const float* __restrict__ b_edge,
    const u16* __restrict__ Wihb, const u16* __restrict__ Whhb,
    const float* __restrict__ gbih, const float* __restrict__ gbhh,
    const u16* __restrict__ recs, const int* __restrict__ rows,
    const u16* __restrict__ WTih0b, const u16* __restrict__ WThh0b,
    const u16* __restrict__ WTih1b, const u16* __restrict__ WThh1b,
    const u16* __restrict__ WTih2b, const u16* __restrict__ WThh2b,
    const float* __restrict__ b_ih0, const float* __restrict__ b_hh0,
    const float* __restrict__ b_ih1, const float* __restrict__ b_hh1,
    const float* __restrict__ b_ih2, const float* __restrict__ b_hh2,
    const float* __restrict__ Wp, const float* __restrict__ bp,
    float* __restrict__ out) {
  __shared__ __align__(16) float h32[NPG * 64];     // fp32 master state      51200B
  __shared__ __align__(16) u16 hb_s[NPAD * 64];     // bf16 mirror (swizzled) 26624B
  __shared__ __align__(16) u16 wh_s[2 * NPG * 64];  // 2-etype Wh / ab alias  51200B
  __shared__ __align__(16) u16 rec_s[EPG];          //                         6400B
  __shared__ int rows_s[3 * (NPG + 1)];             //                         2412B
  // set2set scratch (~8.2KB). Total ~146KB -> 1 block/CU.
  __shared__ float qstar[128], xbuf[64], hs_s[3][64], cs_s[3][64];
  __shared__ float gates[256], gpart[512], e_s[NPG], red[8][64], scal[2];

  int g = blockIdx.x, tid = threadIdx.x;
  int lane = tid & 63, wid = tid >> 6;
  int m = lane & 15, quad = lane >> 4;
  int half = lane >> 5, l32 = lane & 31;

  // ---- stage graph-local state ----
  const float* fg = feats + (size_t)g * (NPG * 64);
  for (int i = tid; i < NPG * 64; i += 512) {
    float v = fg[i];
    h32[i] = v;
    hb_s[swz(i >> 6, i & 63)] = f2bf(v);
  }
  for (int i = tid; i < (NPAD - NPG) * 64; i += 512) hb_s[NPG * 64 + i] = 0;  // pad rows
  {
    const u32* r32 = (const u32*)(recs + (size_t)g * EPG);
    u32* rl = (u32*)rec_s;
    for (int i = tid; i < EPG / 2; i += 512) rl[i] = r32[i];
  }
  for (int i = tid; i < 3 * (NPG + 1); i += 512) rows_s[i] = rows[g * 3 * (NPG + 1) + i];

  // GRU biases, reused every step
  float bir[4], bhr[4], biz[4], bhz[4], bin_[4], bhn[4];
#pragma unroll
  for (int dq = 0; dq < 4; dq++) {
    int d = dq * 16 + m;
    bir[dq] = gbih[d];
    bhr[dq] = gbhh[d];
    biz[dq] = gbih[64 + d];
    bhz[dq] = gbhh[64 + d];
    bin_[dq] = gbih[128 + d];
    bhn[dq] = gbhh[128 + d];
  }

  u16* ab_s = wh_s;  // alias: wh dead once gather finishes
  int ot = wid & 3, hh = wid >> 2;

#pragma unroll 1
  for (int step = 0; step < NSTEPS; step++) {
    float acc0[25], acc1[25];
#pragma unroll
    for (int q = 0; q < 25; q++) {
      acc0[q] = 0.f;
      acc1[q] = 0.f;
    }
#pragma unroll 1
    for (int ph = 0; ph < 3; ph++) {
      __syncthreads();  // wh_s free (prev gather / prev-step GRU ab-reads done)
      // ---- transform etypes {2ph, 2ph+1} -> wh_s; B-fragments hoisted per wave ----
      {
        const u16* bp0 = WeTb + (((2 * ph) * 64 + ot * 16 + m) * 64) + quad * 8;
        const u16* bp1 = WeTb + (((2 * ph + 1) * 64 + ot * 16 + m) * 64) + quad * 8;
        bf16x8 B00 = *(const bf16x8*)bp0;
        bf16x8 B01 = *(const bf16x8*)(bp0 + 32);
        bf16x8 B10 = *(const bf16x8*)bp1;
        bf16x8 B11 = *(const bf16x8*)(bp1 + 32);
        float bias0 = b_edge[(2 * ph) * 64 + ot * 16 + m];
        float bias1 = b_edge[(2 * ph + 1) * 64 + ot * 16 + m];
        for (int nt = hh; nt < NTILES; nt += 2) {  // tl = 0
          int arow = nt * 16 + m;
          bf16x8 a0 = *(const bf16x8*)(hb_s + swz(arow, quad * 8));
          bf16x8 a1 = *(const bf16x8*)(hb_s + swz(arow, quad * 8 + 32));
          f32x4 c = {0.f, 0.f, 0.f, 0.f};
          c = __builtin_amdgcn_mfma_f32_16x16x32_bf16(a0, B00, c, 0, 0, 0);
          c = __builtin_amdgcn_mfma_f32_16x16x32_bf16(a1, B01, c, 0, 0, 0);
#pragma unroll
          for (int r = 0; r < 4; r++) {
            int node = nt * 16 + quad * 4 + r;
            if (node < NPG) wh_s[node * 64 + ot * 16 + m] = f2bf(c[r] + bias0);
          }
        }
        for (int nt = 1 - hh; nt < NTILES; nt += 2) {  // tl = 1
          int arow = nt * 16 + m;
          bf16x8 a0 = *(const bf16x8*)(hb_s + swz(arow, quad * 8));
          bf16x8 a1 = *(const bf16x8*)(hb_s + swz(arow, quad * 8 + 32));
          f32x4 c = {0.f, 0.f, 0.f, 0.f};
          c = __builtin_amdgcn_mfma_f32_16x16x32_bf16(a0, B10, c, 0, 0, 0);
          c = __builtin_amdgcn_mfma_f32_16x16x32_bf16(a1, B11, c, 0, 0, 0);
#pragma unroll
          for (int r = 0; r < 4; r++) {
            int node = nt * 16 + quad * 4 + r;
            if (node < NPG) wh_s[(NPG + node) * 64 + ot * 16 + m] = f2bf(c[r] + bias1);
          }
        }
      }
      __syncthreads();  // wh ready
      // ---- gather: half-wave per edge, u32 (2 cols) per lane ----
      const int* rowp = rows_s + ph * (NPG + 1);
#pragma unroll
      for (int q = 0; q < 25; q++) {
        int n = q * 8 + wid;
        int rs = rowp[n], re = rowp[n + 1];
        float r0 = 0.f, r1 = 0.f;
        int e = rs;
        for (; e + 4 <= re; e += 4) {
          int pA = rec_s[e + half];
          int pB = rec_s[e + 2 + half];
          u32 wA = *(const u32*)(wh_s + pA * 64 + 2 * l32);
          u32 wB = *(const u32*)(wh_s + pB * 64 + 2 * l32);
          r0 += bflo(wA) + bflo(wB);
          r1 += bfhi(wA) + bfhi(wB);
        }
        if (e + 2 <= re) {
          int pA = rec_s[e + half];
          u32 wA = *(const u32*)(wh_s + pA * 64 + 2 * l32);
          r0 += bflo(wA);
          r1 += bfhi(wA);
          e += 2;
        }
        if (e < re && half == 0) {
          int pA = rec_s[e];
          u32 wA = *(const u32*)(wh_s + pA * 64 + 2 * l32);
          r0 += bflo(wA);
          r1 += bfhi(wA);
        }
        acc0[q] += r0;
        acc1[q] += r1;
      }
    }
    __syncthreads();  // all gathers done; reuse wh_s as ab_s
#pragma unroll
    for (int q = 0; q < 25; q++) {
      float s0 = acc0[q] + __shfl_xor(acc0[q], 32);
      float s1 = acc1[q] + __shfl_xor(acc1[q], 32);
      if (lane < 32) {
        int n = q * 8 + wid;
        u32 pk = (u32)f2bf(s0) | ((u32)f2bf(s1) << 16);
        *(u32*)(ab_s + n * 64 + ((2 * l32) ^ ((n & 7) << 3))) = pk;
      }
    }
    __syncthreads();  // ab ready
    // ---- GRU: wave owns node-tiles wid, wid+8 (rows disjoint -> no inner barrier) ----
    for (int nt = wid; nt < NTILES; nt += 8) {
      int arow = nt * 16 + m;
      bf16x8 aa0 = *(const bf16x8*)(ab_s + swz(arow, quad * 8));
      bf16x8 aa1 = *(const bf16x8*)(ab_s + swz(arow, quad * 8 + 32));
      bf16x8 ah0 = *(const bf16x8*)(hb_s + swz(arow, quad * 8));
      bf16x8 ah1 = *(const bf16x8*)(hb_s + swz(arow, quad * 8 + 32));
      f32x4 crz[8], cin[4], chn[4];
#pragma unroll
      for (int jt = 0; jt < 8; jt++) {  // r,z gates: ih+hh summed in one acc
        const u16* bip = Wihb + (jt * 16 + m) * 64 + quad * 8;
        const u16* bhp = Whhb + (jt * 16 + m) * 64 + quad * 8;
        bf16x8 bi0 = *(const bf16x8*)bip;
        bf16x8 bi1 = *(const bf16x8*)(bip + 32);
        bf16x8 bh0 = *(const bf16x8*)bhp;
        bf16x8 bh1 = *(const bf16x8*)(bhp + 32);
        f32x4 c = {0.f, 0.f, 0.f, 0.f};
        c = __builtin_amdgcn_mfma_f32_16x16x32_bf16(ah1, bh1, c, 0, 0, 0);
        c = __builtin_amdgcn_mfma_f32_16x16x32_bf16(ah0, bh0, c, 0, 0, 0);
        c = __builtin_amdgcn_mfma_f32_16x16x32_bf16(aa1, bi1, c, 0, 0, 0);
        c = __builtin_amdgcn_mfma_f32_16x16x32_bf16(aa0, bi0, c, 0, 0, 0);
        crz[jt] = c;
      }
#pragma unroll
      for (int jt = 8; jt < 12; jt++) {  // n gate: ih and hh kept separate
        const u16* bip = Wihb + (jt * 16 + m) * 64 + quad * 8;
        const u16* bhp = Whhb + (jt * 16 + m) * 64 + quad * 8;
        bf16x8 bi0 = *(const bf16x8*)bip;
        bf16x8 bi1 = *(const bf16x8*)(bip + 32);
        bf16x8 bh0 = *(const bf16x8*)bhp;
        bf16x8 bh1 = *(const bf16x8*)(bhp + 32);
        f32x4 z4 = {0.f, 0.f, 0.f, 0.f};
        f32x4 ci = __builtin_amdgcn_mfma_f32_16x16x32_bf16(aa1, bi1, z4, 0, 0, 0);
        cin[jt - 8] = __builtin_amdgcn_mfma_f32_16x16x32_bf16(aa0, bi0, ci, 0, 0, 0);
        f32x4 ch = __builtin_amdgcn_mfma_f32_16x16x32_bf16(ah1, bh1, z4, 0, 0, 0);
        chn[jt - 8] = __builtin_amdgcn_mfma_f32_16x16x32_bf16(ah0, bh0, ch, 0, 0, 0);
      }
#pragma unroll
      for (int r = 0; r < 4; r++) {
        int node = nt * 16 + quad * 4 + r;
        if (node < NPG) {
#pragma unroll
          for (int dq = 0; dq < 4; dq++) {
            int d = dq * 16 + m;
            float rr = sigmf(crz[dq][r] + bir[dq] + bhr[dq]);
            float zz = sigmf(crz[4 + dq][r] + biz[dq] + bhz[dq]);
            float nn = tanhf(cin[dq][r] + bin_[dq] + rr * (chn[dq][r] + bhn[dq]));
            float hv = h32[node * 64 + d];
            float hnew = (1.0f - zz) * nn + zz * hv;
            h32[node * 64 + d] = hnew;
            hb_s[swz(node, d)] = f2bf(hnew);
          }
        }
      }
    }
  }
  __syncthreads();  // final h ready

  // ================= Set2Set (weights register-resident) =================
  int j = tid & 255, part = tid >> 8;  // wave-uniform part
  u32 w0[48], w1[32], w2[32];
  if (part == 0) {
#pragma unroll
    for (int kk = 0; kk < 48; kk++)
      w0[kk] = (u32)WTih0b[(2 * kk) * 256 + j] | ((u32)WTih0b[(2 * kk + 1) * 256 + j] << 16);
  } else {
#pragma unroll
    for (int kk = 0; kk < 16; kk++)
      w0[kk] = (u32)WTih0b[(96 + 2 * kk) * 256 + j] | ((u32)WTih0b[(97 + 2 * kk) * 256 + j] << 16);
#pragma unroll
    for (int kk = 0; kk < 32; kk++)
      w0[16 + kk] = (u32)WThh0b[(2 * kk) * 256 + j] | ((u32)WThh0b[(2 * kk + 1) * 256 + j] << 16);
  }
  {
    const u16* W1 = part ? WThh1b : WTih1b;
    const u16* W2 = part ? WThh2b : WTih2b;
#pragma unroll
    for (int kk = 0; kk < 32; kk++) {
      w1[kk] = (u32)W1[(2 * kk) * 256 + j] | ((u32)W1[(2 * kk + 1) * 256 + j] << 16);
      w2[kk] = (u32)W2[(2 * kk) * 256 + j] | ((u32)W2[(2 * kk + 1) * 256 + j] << 16);
    }
  }
  float bs0 = 0.f, bs1 = 0.f, bs2 = 0.f;
  if (tid < 256) {
    bs0 = b_ih0[tid] + b_hh0[tid];
    bs1 = b_ih1[tid] + b_hh1[tid];
    bs2 = b_ih2[tid] + b_hh2[tid];
  }
  if (tid < 128) qstar[tid] = 0.f;
  if (tid < 64) {
    xbuf[tid] = 0.f;
    for (int l = 0; l < 3; l++) {
      hs_s[l][tid] = 0.f;
      cs_s[l][tid] = 0.f;
    }
  }
  __syncthreads();
#pragma unroll 1
  for (int it = 0; it < NITERS; it++) {
    // ---- layer 0: K=192 split (part0: qstar k<96; part1: qstar 96..127 + hs0) ----
    {
      float a0 = 0.f, a1 = 0.f;
      if (part == 0) {
#pragma unroll
        for (int kk = 0; kk < 48; kk++) {
          u32 w = w0[kk];
          a0 += qstar[2 * kk] * bflo(w);
          a1 += qstar[2 * kk + 1] * bfhi(w);
        }
      } else {
#pragma unroll
        for (int kk = 0; kk < 16; kk++) {
          u32 w = w0[kk];
          a0 += qstar[96 + 2 * kk] * bflo(w);
          a1 += qstar[97 + 2 * kk] * bfhi(w);
        }
#pragma unroll
        for (int kk = 0; kk < 32; kk++) {
          u32 w = w0[16 + kk];
          a0 += hs_s[0][2 * kk] * bflo(w);
          a1 += hs_s[0][2 * kk + 1] * bfhi(w);
        }
      }
      gpart[part * 256 + j] = a0 + a1;
    }
    __syncthreads();
    if (tid < 256) gates[tid] = gpart[tid] + gpart[256 + tid] + bs0;
    __syncthreads();
    if (tid < 64) {
      float cc = sigmf(gates[64 + tid]) * cs_s[0][tid] + sigmf(gates[tid]) * tanhf(gates[128 + tid]);
      float x = sigmf(gates[192 + tid]) * tanhf(cc);
      cs_s[0][tid] = cc;
      hs_s[0][tid] = x;
      xbuf[tid] = x;
    }
    __syncthreads();
    // ---- layer 1 ----
    {
      const float* xv = part ? hs_s[1] : xbuf;
      float a0 = 0.f, a1 = 0.f;
#pragma unroll
      for (int kk = 0; kk < 32; kk++) {
        u32 w = w1[kk];
        a0 += xv[2 * kk] * bflo(w);
        a1 += xv[2 * kk + 1] * bfhi(w);
      }
      gpart[part * 256 + j] = a0 + a1;
    }
    __syncthreads();
    if (tid < 256) gates[tid] = gpart[tid] + gpart[256 + tid] + bs1;
    __syncthreads();
    if (tid < 64) {
      float cc = sigmf(gates[64 + tid]) * cs_s[1][tid] + sigmf(gates[tid]) * tanhf(gates[128 + tid]);
      float x = sigmf(gates[192 + tid]) * tanhf(cc);
      cs_s[1][tid] = cc;
      hs_s[1][tid] = x;
      xbuf[tid] = x;
    }
    __syncthreads();
    // ---- layer 2 ----
    {
      const float* xv = part ? hs_s[2] : xbuf;
      float a0 = 0.f, a1 = 0.f;
#pragma unroll
      for (int kk = 0; kk < 32; kk++) {
        u32 w = w2[kk];
        a0 += xv[2 * kk] * bflo(w);
        a1 += xv[2 * kk + 1] * bfhi(w);
      }
      gpart[part * 256 + j] = a0 + a1;
    }
    __syncthreads();
    if (tid < 256) gates[tid] = gpart[tid] + gpart[256 + tid] + bs2;
    __syncthreads();
    if (tid < 64) {
      float cc = sigmf(gates[64 + tid]) * cs_s[2][tid] + sigmf(gates[tid]) * tanhf(gates[128 + tid]);
      float x = sigmf(gates[192 + tid]) * tanhf(cc);
      cs_s[2][tid] = cc;
      hs_s[2][tid] = x;
      xbuf[tid] = x;
    }
    __syncthreads();
    // ---- attention over this graph's nodes (feat == h32) ----
    for (int n = wid; n < NPG; n += 8) {
      float v = h32[n * 64 + lane] * xbuf[lane];
      for (int off = 32; off > 0; off >>= 1) v += __shfl_down(v, off);
      if (lane == 0) e_s[n] = v;
    }
    __syncthreads();
    if (tid < 64) {
      float mx = -1e30f;
      for (int n = lane; n < NPG; n += 64) mx = fmaxf(mx, e_s[n]);
      for (int off = 32; off > 0; off >>= 1) mx = fmaxf(mx, __shfl_down(mx, off));
      mx = __shfl(mx, 0);
      float ssum = 0.f;
      for (int n = lane; n < NPG; n += 64) {
        float ex = __expf(e_s[n] - mx);
        e_s[n] = ex;
        ssum += ex;
      }
      for (int off = 32; off > 0; off >>= 1) ssum += __shfl_down(ssum, off);
      if (lane == 0) scal[0] = ssum;
    }
    __syncthreads();
    float denom = scal[0];
    {
      float r = 0.f;
      for (int n = wid; n < NPG; n += 8) r += h32[n * 64 + lane] * e_s[n];
      red[wid][lane] = r;
    }
    __syncthreads();
    if (tid < 64) {
      float ro = 0.f;
#pragma unroll
      for (int ww = 0; ww < 8; ww++) ro += red[ww][lane];
      qstar[lane] = xbuf[lane];
      qstar[64 + lane] = ro / denom;
    }
    __syncthreads();
  }
  if (tid < 3) {
    float s = bp[tid];
    for (int k = 0; k < 128; k++) s += qstar[k] * Wp[tid * 128 + k];
    out[g * 3 + tid] = s;
  }
}

// ---------------- host ----------------

extern "C" void kernel_launch(void* const* d_in, const int* in_sizes, int n_in,
                              void* d_out, int out_size, void* d_ws, size_t ws_size,
                              hipStream_t stream) {
  const float* feats  = (const float*)d_in[0];
  const float* W_edge = (const float*)d_in[1];
  const float* b_edge = (const float*)d_in[2];
  const float* gWih   = (const float*)d_in[3];
  const float* gWhh   = (const float*)d_in[4];
  const float* gbih   = (const float*)d_in[5];
  const float* gbhh   = (const float*)d_in[6];
  const float* lWi0   = (const float*)d_in[7];
  const float* lWh0   = (const float*)d_in[8];
  const float* lbi0   = (const float*)d_in[9];
  const float* lbh0   = (const float*)d_in[10];
  const float* lWi1   = (const float*)d_in[11];
  const float* lWh1   = (const float*)d_in[12];
  const float* lbi1   = (const float*)d_in[13];
  const float* lbh1   = (const float*)d_in[14];
  const float* lWi2   = (const float*)d_in[15];
  const float* lWh2   = (const float*)d_in[16];
  const float* lbi2   = (const float*)d_in[17];
  const float* lbh2   = (const float*)d_in[18];
  const float* Wp     = (const float*)d_in[19];
  const float* bp     = (const float*)d_in[20];
  const int* src      = (const int*)d_in[21];
  const int* dst      = (const int*)d_in[22];
  const int* ety      = (const int*)d_in[23];
  float* out = (float*)d_out;

  char* ws = (char*)d_ws;
  u16* recs    = (u16*)ws;              // 2,048,000 B
  int* rows    = (int*)(ws + 2048000);  //   771,840 B (320 x 3 x 201)
  u16* WeTb    = (u16*)(ws + 2819840);  //    49,152 B
  u16* Wihb    = (u16*)(ws + 2868992);  //    24,576 B
  u16* Whhb    = (u16*)(ws + 2893568);  //    24,576 B
  u16* WTih0b  = (u16*)(ws + 2918144);  //    65,536 B
  u16* WThh0b  = (u16*)(ws + 2983680);  //    32,768 B
  u16* WTih1b  = (u16*)(ws + 3016448);  //    32,768 B
  u16* WThh1b  = (u16*)(ws + 3049216);  //    32,768 B
  u16* WTih2b  = (u16*)(ws + 3081984);  //    32,768 B
  u16* WThh2b  = (u16*)(ws + 3114752);  //    32,768 B

  k_csr<<<NGRAPH, 256, 0, stream>>>(src, dst, ety, recs, rows);
  k_prep<<<640, 256, 0, stream>>>(W_edge, gWih, gWhh, lWi0, lWh0, lWi1, lWh1, lWi2, lWh2,
                                  WeTb, Wihb, Whhb, WTih0b, WThh0b, WTih1b, WThh1b, WTih2b, WThh2b);
  k_ggnn<<<NGRAPH, 512, 0, stream>>>(feats, WeTb, b_edge, Wihb, Whhb, gbih, gbhh, recs, rows,
                                     WTih0b, WThh0b, WTih1b, WThh1b, WTih2b, WThh2b,
                                     lbi0, lbh0, lbi1, lbh1, lbi2, lbh2, Wp, bp, out);
}

// Round 5
// 915.794 us; speedup vs baseline: 1.1181x; 1.1181x over previous
//
#include <hip/hip_runtime.h>

typedef unsigned short u16;
typedef unsigned int u32;

#define DIM 64
#define NGRAPH 320
#define NPG 200
#define EPG 3200
#define NSTEPS 5
#define NITERS 6
#define NTILES 13  // ceil(200/16)
#define NPAD 208   // NTILES*16

typedef __attribute__((ext_vector_type(8))) short bf16x8;
typedef __attribute__((ext_vector_type(4))) float f32x4;

__device__ __forceinline__ float bf2f(u16 u) {
  u32 x = ((u32)u) << 16;
  float f;
  __builtin_memcpy(&f, &x, 4);
  return f;
}
__device__ __forceinline__ u16 f2bf(float f) {
  u32 x;
  __builtin_memcpy(&x, &f, 4);
  x = (x + 0x7FFFu + ((x >> 16) & 1u)) >> 16;
  return (u16)x;
}
__device__ __forceinline__ float bflo(u32 w) {
  u32 x = w << 16;
  float f;
  __builtin_memcpy(&f, &x, 4);
  return f;
}
__device__ __forceinline__ float bfhi(u32 w) {
  u32 x = w & 0xffff0000u;
  float f;
  __builtin_memcpy(&f, &x, 4);
  return f;
}
__device__ __forceinline__ float sigmf(float x) { return 1.0f / (1.0f + __expf(-x)); }
// XOR swizzle for bf16 [row][64] LDS tiles read as ds_read_b128 at 128B row stride.
__device__ __forceinline__ int swz(int row, int col) { return row * 64 + (col ^ ((row & 7) << 3)); }

// ---------------- prep ----------------

// 3-phase CSR: phase p = etype>>1, local t = etype&1. rec = t*NPG + src (direct wh row id).
__global__ void __launch_bounds__(256) k_csr(const int* __restrict__ src,
                                             const int* __restrict__ dst,
                                             const int* __restrict__ ety,
                                             u16* __restrict__ recs,
                                             int* __restrict__ rows) {
  __shared__ int cnt[3 * NPG];
  __shared__ int rofs[3 * (NPG + 1)];
  int g = blockIdx.x, tid = threadIdx.x;
  int base = g * NPG;
  for (int i = tid; i < 3 * NPG; i += 256) cnt[i] = 0;
  __syncthreads();
  for (int e = tid; e < EPG; e += 256) {
    int d = dst[g * EPG + e] - base;
    int t = ety[g * EPG + e];
    atomicAdd(&cnt[(t >> 1) * NPG + d], 1);
  }
  __syncthreads();
  if (tid == 0) {
    int s = 0;
    for (int p = 0; p < 3; p++) {
      for (int n = 0; n < NPG; n++) {
        rofs[p * (NPG + 1) + n] = s;
        s += cnt[p * NPG + n];
      }
      rofs[p * (NPG + 1) + NPG] = s;
    }
  }
  __syncthreads();
  for (int i = tid; i < 3 * NPG; i += 256) cnt[i] = rofs[(i / NPG) * (NPG + 1) + (i % NPG)];
  __syncthreads();
  for (int e = tid; e < EPG; e += 256) {
    int d = dst[g * EPG + e] - base;
    int t = ety[g * EPG + e];
    int sl = src[g * EPG + e] - base;
    int pos = atomicAdd(&cnt[(t >> 1) * NPG + d], 1);
    recs[g * EPG + pos] = (u16)((t & 1) * NPG + sl);
  }
  for (int i = tid; i < 3 * (NPG + 1); i += 256) rows[g * 3 * (NPG + 1) + i] = rofs[i];
}

// All weight conversions/transposes in ONE launch (163840 elems = 640 x 256).
__global__ void __launch_bounds__(256) k_prep(
    const float* __restrict__ W_edge, const float* __restrict__ gWih, const float* __restrict__ gWhh,
    const float* __restrict__ lWi0, const float* __restrict__ lWh0,
    const float* __restrict__ lWi1, const float* __restrict__ lWh1,
    const float* __restrict__ lWi2, const float* __restrict__ lWh2,
    u16* __restrict__ WeTb, u16* __restrict__ Wihb, u16* __restrict__ Whhb,
    u16* __restrict__ WTih0b, u16* __restrict__ WThh0b,
    u16* __restrict__ WTih1b, u16* __restrict__ WThh1b,
    u16* __restrict__ WTih2b, u16* __restrict__ WThh2b) {
  int i = blockIdx.x * 256 + threadIdx.x;
  if (i < 24576) {  // WeT: [t][o][k] <- W_edge[t][k][o]
    int t = i >> 12, rem = i & 4095, o = rem >> 6, k = rem & 63;
    WeTb[i] = f2bf(W_edge[t * 4096 + k * 64 + o]);
  } else if (i < 36864) {
    int idx = i - 24576;
    Wihb[idx] = f2bf(gWih[idx]);
  } else if (i < 49152) {
    int idx = i - 36864;
    Whhb[idx] = f2bf(gWhh[idx]);
  } else if (i < 81920) {  // WTih0: [k<128][j<256] <- lWi0[j][k]
    int idx = i - 49152;
    int k = idx >> 8, jj = idx & 255;
    WTih0b[idx] = f2bf(lWi0[jj * 128 + k]);
  } else {  // five [k<64][j<256] transposes
    int idx = i - 81920;
    int seg = idx >> 14;
    int r = idx & 16383;
    int k = r >> 8, jj = r & 255;
    const float* sp = seg == 0 ? lWh0 : seg == 1 ? lWi1 : seg == 2 ? lWh1 : seg == 3 ? lWi2 : lWh2;
    u16* dp = seg == 0 ? WThh0b : seg == 1 ? WTih1b : seg == 2 ? WThh1b : seg == 3 ? WTih2b : WThh2b;
    dp[r] = f2bf(sp[jj * 64 + k]);
  }
}

// ---------------- fully fused GGNN + Set2Set: one block = one graph ----------------
// R4/R5: no per-thread arrays with long live ranges (R1-R3 spilled ~165MB of
// scratch: gather accumulators 200B/thread/step -> local memory). Gather
// accumulates into an f32 LDS buffer; fp32 h state lives in statically-indexed
// registers (same thread owns the same (node,d) every step).

__global__ void __launch_bounds__(512, 1) k_ggnn(
    const float* __restrict__ feats,
    const u16* __restrict__ WeTb, const float* __restrict__ b_edge,
    const u16* __restrict__ Wihb, const u16* __restrict__ Whhb,
    const float* __restrict__ gbih, const float* __restrict__ gbhh,
    const u16* __restrict__ recs, const int* __restrict__ rows,
    const u16* __restrict__ WTih0b, const u16* __restrict__ WThh0b,
    const u16* __restrict__ WTih1b, const u16* __restrict__ WThh1b,
    const u16* __restrict__ WTih2b, const u16* __restrict__ WThh2b,
    const float* __restrict__ b_ih0, const float* __restrict__ b_hh0,
    const float* __restrict__ b_ih1, const float* __restrict__ b_hh1,
    const float* __restrict__ b_ih2, const float* __restrict__ b_hh2,
    const float* __restrict__ Wp, const float* __restrict__ bp,
    float* __restrict__ out) {
  __shared__ __align__(16) u16 hb_s[NPAD * 64];     // bf16 h (swizzled)       26624B
  __shared__ __align__(16) u16 wh_s[2 * NPG * 64];  // 2-etype Wh / ab alias   51200B
  __shared__ __align__(16) float acc_s[NPG * 64];   // f32 gather acc / feat_s 51200B
  __shared__ __align__(16) u16 rec_s[EPG];          //                          6400B
  __shared__ int rows_s[3 * (NPG + 1)];             //                          2412B
  // set2set scratch (~8.2KB). Total ~146KB -> 1 block/CU.
  __shared__ float qstar[128], xbuf[64], hs_s[3][64], cs_s[3][64];
  __shared__ float gates[256], gpart[512], e_s[NPG], red[8][64], scal[2];

  int g = blockIdx.x, tid = threadIdx.x;
  int lane = tid & 63, wid = tid >> 6;
  int m = lane & 15, quad = lane >> 4;
  int half = lane >> 5, l32 = lane & 31;

  // ---- stage graph-local state ----
  const float* fg = feats + (size_t)g * (NPG * 64);
  for (int i = tid; i < NPG * 64; i += 512) hb_s[swz(i >> 6, i & 63)] = f2bf(fg[i]);
  for (int i = tid; i < (NPAD - NPG) * 64; i += 512) hb_s[NPG * 64 + i] = 0;  // pad rows
  {
    const u32* r32 = (const u32*)(recs + (size_t)g * EPG);
    u32* rl = (u32*)rec_s;
    for (int i = tid; i < EPG / 2; i += 512) rl[i] = r32[i];
  }
  for (int i = tid; i < 3 * (NPG + 1); i += 512) rows_s[i] = rows[g * 3 * (NPG + 1) + i];

  // fp32 h in registers: thread owns (node = nt*16+quad*4+r, d = dq*16+m),
  // nt = wid + 8*ti. Static indexing throughout.
  float hreg[2][4][4] = {};
#pragma unroll
  for (int ti = 0; ti < 2; ti++) {
    int nt = wid + 8 * ti;
    if (nt < NTILES) {
#pragma unroll
      for (int r = 0; r < 4; r++) {
        int node = nt * 16 + quad * 4 + r;
        if (node < NPG) {
#pragma unroll
          for (int dq = 0; dq < 4; dq++) hreg[ti][r][dq] = fg[node * 64 + dq * 16 + m];
        }
      }
    }
  }

  u16* ab_s = wh_s;  // alias: wh dead once gathers finish
  int ot = wid & 3, hh = wid >> 2;

#pragma unroll 1
  for (int step = 0; step < NSTEPS; step++) {
    __syncthreads();  // prev GRU done (step>0) / staging done (step 0); acc_s dead
    // ---- zero f32 accumulator ----
    {
      float4* z4 = (float4*)acc_s;
      float4 z = {0.f, 0.f, 0.f, 0.f};
      for (int i = tid; i < NPG * 16; i += 512) z4[i] = z;
    }
#pragma unroll 1
    for (int ph = 0; ph < 3; ph++) {
      if (ph > 0) __syncthreads();  // gather of ph-1 done reading wh_s
      // ---- transform etypes {2ph, 2ph+1} -> wh_s; B-fragments hoisted per wave ----
      {
        const u16* bp0 = WeTb + (((2 * ph) * 64 + ot * 16 + m) * 64) + quad * 8;
        const u16* bp1 = WeTb + (((2 * ph + 1) * 64 + ot * 16 + m) * 64) + quad * 8;
        bf16x8 B00 = *(const bf16x8*)bp0;
        bf16x8 B01 = *(const bf16x8*)(bp0 + 32);
        bf16x8 B10 = *(const bf16x8*)bp1;
        bf16x8 B11 = *(const bf16x8*)(bp1 + 32);
        float bias0 = b_edge[(2 * ph) * 64 + ot * 16 + m];
        float bias1 = b_edge[(2 * ph + 1) * 64 + ot * 16 + m];
        for (int nt = hh; nt < NTILES; nt += 2) {  // tl = 0
          int arow = nt * 16 + m;
          bf16x8 a0 = *(const bf16x8*)(hb_s + swz(arow, quad * 8));
          bf16x8 a1 = *(const bf16x8*)(hb_s + swz(arow, quad * 8 + 32));
          f32x4 c = {0.f, 0.f, 0.f, 0.f};
          c = __builtin_amdgcn_mfma_f32_16x16x32_bf16(a0, B00, c, 0, 0, 0);
          c = __builtin_amdgcn_mfma_f32_16x16x32_bf16(a1, B01, c, 0, 0, 0);
#pragma unroll
          for (int r = 0; r < 4; r++) {
            int node = nt * 16 + quad * 4 + r;
            if (node < NPG) wh_s[node * 64 + ot * 16 + m] = f2bf(c[r] + bias0);
          }
        }
        for (int nt = 1 - hh; nt < NTILES; nt += 2) {  // tl = 1
          int arow = nt * 16 + m;
          bf16x8 a0 = *(const bf16x8*)(hb_s + swz(arow, quad * 8));
          bf16x8 a1 = *(const bf16x8*)(hb_s + swz(arow, quad * 8 + 32));
          f32x4 c = {0.f, 0.f, 0.f, 0.f};
          c = __builtin_amdgcn_mfma_f32_16x16x32_bf16(a0, B10, c, 0, 0, 0);
          c = __builtin_amdgcn_mfma_f32_16x16x32_bf16(a1, B11, c, 0, 0, 0);
#pragma unroll
          for (int r = 0; r < 4; r++) {
            int node = nt * 16 + quad * 4 + r;
            if (node < NPG) wh_s[(NPG + node) * 64 + ot * 16 + m] = f2bf(c[r] + bias1);
          }
        }
      }
      __syncthreads();  // wh ready (and, for ph==0, acc zero done)
      // ---- gather: half-wave per edge, u32 (2 cols) per lane; += into acc_s ----
      const int* rowp = rows_s + ph * (NPG + 1);
      for (int q = 0; q < 25; q++) {
        int n = q * 8 + wid;
        int rs = rowp[n], re = rowp[n + 1];
        float r0 = 0.f, r1 = 0.f;
        int e = rs;
        for (; e + 4 <= re; e += 4) {
          int pA = rec_s[e + half];
          int pB = rec_s[e + 2 + half];
          u32 wA = *(const u32*)(wh_s + pA * 64 + 2 * l32);
          u32 wB = *(const u32*)(wh_s + pB * 64 + 2 * l32);
          r0 += bflo(wA) + bflo(wB);
          r1 += bfhi(wA) + bfhi(wB);
        }
        if (e + 2 <= re) {
          int pA = rec_s[e + half];
          u32 wA = *(const u32*)(wh_s + pA * 64 + 2 * l32);
          r0 += bflo(wA);
          r1 += bfhi(wA);
          e += 2;
        }
        if (e < re && half == 0) {
          int pA = rec_s[e];
          u32 wA = *(const u32*)(wh_s + pA * 64 + 2 * l32);
          r0 += bflo(wA);
          r1 += bfhi(wA);
        }
        r0 += __shfl_xor(r0, 32);
        r1 += __shfl_xor(r1, 32);
        if (lane < 32) {
          float2* p = (float2*)(acc_s + n * 64 + 2 * l32);
          float2 v = *p;
          v.x += r0;
          v.y += r1;
          *p = v;
        }
      }
    }
    __syncthreads();  // all gathers done; acc_s final; wh_s free -> ab_s
    // ---- convert acc_s -> ab_s (swizzled bf16) ----
    for (int idx = tid; idx < NPG * 32; idx += 512) {
      int n = idx >> 5, jj = idx & 31;
      float2 v = *(const float2*)(acc_s + n * 64 + 2 * jj);
      u32 pk = (u32)f2bf(v.x) | ((u32)f2bf(v.y) << 16);
      *(u32*)(ab_s + n * 64 + ((2 * jj) ^ ((n & 7) << 3))) = pk;
    }
    __syncthreads();  // ab ready
    // ---- GRU: per-dq gate fragments (16 acc regs), epilogue immediate ----
#pragma unroll
    for (int ti = 0; ti < 2; ti++) {
      int nt = wid + 8 * ti;
      if (nt >= NTILES) continue;
      int arow = nt * 16 + m;
      bf16x8 aa0 = *(const bf16x8*)(ab_s + swz(arow, quad * 8));
      bf16x8 aa1 = *(const bf16x8*)(ab_s + swz(arow, quad * 8 + 32));
      bf16x8 ah0 = *(const bf16x8*)(hb_s + swz(arow, quad * 8));
      bf16x8 ah1 = *(const bf16x8*)(hb_s + swz(arow, quad * 8 + 32));
#pragma unroll
      for (int dq = 0; dq < 4; dq++) {
        int d = dq * 16 + m;
        f32x4 z4 = {0.f, 0.f, 0.f, 0.f};
        // r gate (jt = dq): ih + hh chained into one acc
        const u16* bi = Wihb + (dq * 16 + m) * 64 + quad * 8;
        const u16* bh = Whhb + (dq * 16 + m) * 64 + quad * 8;
        f32x4 cr = z4;
        {
          bf16x8 b0 = *(const bf16x8*)bi, b1 = *(const bf16x8*)(bi + 32);
          bf16x8 c0 = *(const bf16x8*)bh, c1 = *(const bf16x8*)(bh + 32);
          cr = __builtin_amdgcn_mfma_f32_16x16x32_bf16(ah0, c0, cr, 0, 0, 0);
          cr = __builtin_amdgcn_mfma_f32_16x16x32_bf16(ah1, c1, cr, 0, 0, 0);
          cr = __builtin_amdgcn_mfma_f32_16x16x32_bf16(aa0, b0, cr, 0, 0, 0);
          cr = __builtin_amdgcn_mfma_f32_16x16x32_bf16(aa1, b1, cr, 0, 0, 0);
        }
        // z gate (jt = 4+dq)
        const u16* bi2 = Wihb + ((4 + dq) * 16 + m) * 64 + quad * 8;
        const u16* bh2 = Whhb + ((4 + dq) * 16 + m) * 64 + quad * 8;
        f32x4 cz = z4;
        {
          bf16x8 b0 = *(const bf16x8*)bi2, b1 = *(const bf16x8*)(bi2 + 32);
          bf16x8 c0 = *(const bf16x8*)bh2, c1 = *(const bf16x8*)(bh2 + 32);
          cz = __builtin_amdgcn_mfma_f32_16x16x32_bf16(ah0, c0, cz, 0, 0, 0);
          cz = __builtin_amdgcn_mfma_f32_16x16x32_bf16(ah1, c1, cz, 0, 0, 0);
          cz = __builtin_amdgcn_mfma_f32_16x16x32_bf16(aa0, b0, cz, 0, 0, 0);
          cz = __builtin_amdgcn_mfma_f32_16x16x32_bf16(aa1, b1, cz, 0, 0, 0);
        }
        // n gate (jt = 8+dq): ih and hh separate
        const u16* bi3 = Wihb + ((8 + dq) * 16 + m) * 64 + quad * 8;
        const u16* bh3 = Whhb + ((8 + dq) * 16 + m) * 64 + quad * 8;
        f32x4 ci = z4, ch = z4;
        {
          bf16x8 b0 = *(const bf16x8*)bi3, b1 = *(const bf16x8*)(bi3 + 32);
          bf16x8 c0 = *(const bf16x8*)bh3, c1 = *(const bf16x8*)(bh3 + 32);
          ci = __builtin_amdgcn_mfma_f32_16x16x32_bf16(aa0, b0, ci, 0, 0, 0);
          ci = __builtin_amdgcn_mfma_f32_16x16x32_bf16(aa1, b1, ci, 0, 0, 0);
          ch = __builtin_amdgcn_mfma_f32_16x16x32_bf16(ah0, c0, ch, 0, 0, 0);
          ch = __builtin_amdgcn_mfma_f32_16x16x32_bf16(ah1, c1, ch, 0, 0, 0);
        }
        float bi_r = gbih[d], bh_r = gbhh[d];
        float bi_z = gbih[64 + d], bh_z = gbhh[64 + d];
        float bi_n = gbih[128 + d], bh_n = gbhh[128 + d];
#pragma unroll
        for (int r = 0; r < 4; r++) {
          int node = nt * 16 + quad * 4 + r;
          if (node < NPG) {
            float rr = sigmf(cr[r] + bi_r + bh_r);
            float zz = sigmf(cz[r] + bi_z + bh_z);
            float nn = tanhf(ci[r] + bi_n + rr * (ch[r] + bh_n));
            float hv = hreg[ti][r][dq];
            float hnew = (1.0f - zz) * nn + zz * hv;
            hreg[ti][r][dq] = hnew;
            hb_s[swz(node, d)] = f2bf(hnew);
            if (step == NSTEPS - 1) acc_s[node * 64 + d] = hnew;  // feat_s for set2set
          }
        }
      }
    }
  }
  __syncthreads();  // final h (feat_s = acc_s) ready
  const float* feat_s = acc_s;

  // ================= Set2Set (weights register-resident) =================
  int j = tid & 255, part = tid >> 8;  // wave-uniform part
  u32 w0[48], w1[32], w2[32];
  if (part == 0) {
#pragma unroll
    for (int kk = 0; kk < 48; kk++)
      w0[kk] = (u32)WTih0b[(2 * kk) * 256 + j] | ((u32)WTih0b[(2 * kk + 1) * 256 + j] << 16);
  } else {
#pragma unroll
    for (int kk = 0; kk < 16; kk++)
      w0[kk] = (u32)WTih0b[(96 + 2 * kk) * 256 + j] | ((u32)WTih0b[(97 + 2 * kk) * 256 + j] << 16);
#pragma unroll
    for (int kk = 0; kk < 32; kk++)
      w0[16 + kk] = (u32)WThh0b[(2 * kk) * 256 + j] | ((u32)WThh0b[(2 * kk + 1) * 256 + j] << 16);
  }
  {
    const u16* W1 = part ? WThh1b : WTih1b;
    const u16* W2 = part ? WThh2b : WTih2b;
#pragma unroll
    for (int kk = 0; kk < 32; kk++) {
      w1[kk] = (u32)W1[(2 * kk) * 256 + j] | ((u32)W1[(2 * kk + 1) * 256 + j] << 16);
      w2[kk] = (u32)W2[(2 * kk) * 256 + j] | ((u32)W2[(2 * kk + 1) * 256 + j] << 16);
    }
  }
  float bs0 = 0.f, bs1 = 0.f, bs2 = 0.f;
  if (tid < 256) {
    bs0 = b_ih0[tid] + b_hh0[tid];
    bs1 = b_ih1[tid] + b_hh1[tid];
    bs2 = b_ih2[tid] + b_hh2[tid];
  }
  if (tid < 128) qstar[tid] = 0.f;
  if (tid < 64) {
    xbuf[tid] = 0.f;
    for (int l = 0; l < 3; l++) {
      hs_s[l][tid] = 0.f;
      cs_s[l][tid] = 0.f;
    }
  }
  __syncthreads();
#pragma unroll 1
  for (int it = 0; it < NITERS; it++) {
    // ---- layer 0: K=192 split (part0: qstar k<96; part1: qstar 96..127 + hs0) ----
    {
      float a0 = 0.f, a1 = 0.f;
      if (part == 0) {
#pragma unroll
        for (int kk = 0; kk < 48; kk++) {
          u32 w = w0[kk];
          a0 += qstar[2 * kk] * bflo(w);
          a1 += qstar[2 * kk + 1] * bfhi(w);
        }
      } else {
#pragma unroll
        for (int kk = 0; kk < 16; kk++) {
          u32 w = w0[kk];
          a0 += qstar[96 + 2 * kk] * bflo(w);
          a1 += qstar[97 + 2 * kk] * bfhi(w);
        }
#pragma unroll
        for (int kk = 0; kk < 32; kk++) {
          u32 w = w0[16 + kk];
          a0 += hs_s[0][2 * kk] * bflo(w);
          a1 += hs_s[0][2 * kk + 1] * bfhi(w);
        }
      }
      gpart[part * 256 + j] = a0 + a1;
    }
    __syncthreads();
    if (tid < 256) gates[tid] = gpart[tid] + gpart[256 + tid] + bs0;
    __syncthreads();
    if (tid < 64) {
      float cc = sigmf(gates[64 + tid]) * cs_s[0][tid] + sigmf(gates[tid]) * tanhf(gates[128 + tid]);
      float x = sigmf(gates[192 + tid]) * tanhf(cc);
      cs_s[0][tid] = cc;
      hs_s[0][tid] = x;
      xbuf[tid] = x;
    }
    __syncthreads();
    // ---- layer 1 ----
    {
      const float* xv = part ? hs_s[1] : xbuf;
      float a0 = 0.f, a1 = 0.f;
#pragma unroll
      for (int kk = 0; kk < 32; kk++) {
        u32 w = w1[kk];
        a0 += xv[2 * kk] * bflo(w);
        a1 += xv[2 * kk + 1] * bfhi(w);
      }
      gpart[part * 256 + j] = a0 + a1;
    }
    __syncthreads();
    if (tid < 256) gates[tid] = gpart[tid] + gpart[256 + tid] + bs1;
    __syncthreads();
    if (tid < 64) {
      float cc = sigmf(gates[64 + tid]) * cs_s[1][tid] + sigmf(gates[tid]) * tanhf(gates[128 + tid]);
      float x = sigmf(gates[192 + tid]) * tanhf(cc);
      cs_s[1][tid] = cc;
      hs_s[1][tid] = x;
      xbuf[tid] = x;
    }
    __syncthreads();
    // ---- layer 2 ----
    {
      const float* xv = part ? hs_s[2] : xbuf;
      float a0 = 0.f, a1 = 0.f;
#pragma unroll
      for (int kk = 0; kk < 32; kk++) {
        u32 w = w2[kk];
        a0 += xv[2 * kk] * bflo(w);
        a1 += xv[2 * kk + 1] * bfhi(w);
      }
      gpart[part * 256 + j] = a0 + a1;
    }
    __syncthreads();
    if (tid < 256) gates[tid] = gpart[tid] + gpart[256 + tid] + bs2;
    __syncthreads();
    if (tid < 64) {
      float cc = sigmf(gates[64 + tid]) * cs_s[2][tid] + sigmf(gates[tid]) * tanhf(gates[128 + tid]);
      float x = sigmf(gates[192 + tid]) * tanhf(cc);
      cs_s[2][tid] = cc;
      hs_s[2][tid] = x;
      xbuf[tid] = x;
    }
    __syncthreads();
    // ---- attention over this graph's nodes ----
    for (int n = wid; n < NPG; n += 8) {
      float v = feat_s[n * 64 + lane] * xbuf[lane];
      for (int off = 32; off > 0; off >>= 1) v += __shfl_down(v, off);
      if (lane == 0) e_s[n] = v;
    }
    __syncthreads();
    if (tid < 64) {
      float mx = -1e30f;
      for (int n = lane; n < NPG; n += 64) mx = fmaxf(mx, e_s[n]);
      for (int off = 32; off > 0; off >>= 1) mx = fmaxf(mx, __shfl_down(mx, off));
      mx = __shfl(mx, 0);
      float ssum = 0.f;
      for (int n = lane; n < NPG; n += 64) {
        float ex = __expf(e_s[n] - mx);
        e_s[n] = ex;
        ssum += ex;
      }
      for (int off = 32; off > 0; off >>= 1) ssum += __shfl_down(ssum, off);
      if (lane == 0) scal[0] = ssum;
    }
    __syncthreads();
    float denom = scal[0];
    {
      float r = 0.f;
      for (int n = wid; n < NPG; n += 8) r += feat_s[n * 64 + lane] * e_s[n];
      red[wid][lane] = r;
    }
    __syncthreads();
    if (tid < 64) {
      float ro = 0.f;
#pragma unroll
      for (int ww = 0; ww < 8; ww++) ro += red[ww][lane];
      qstar[lane] = xbuf[lane];
      qstar[64 + lane] = ro / denom;
    }
    __syncthreads();
  }
  if (tid < 3) {
    float s = bp[tid];
    for (int k = 0; k < 128; k++) s += qstar[k] * Wp[tid * 128 + k];
    out[g * 3 + tid] = s;
  }
}

// ---------------- host ----------------

extern "C" void kernel_launch(void* const* d_in, const int* in_sizes, int n_in,
                              void* d_out, int out_size, void* d_ws, size_t ws_size,
                              hipStream_t stream) {
  const float* feats  = (const float*)d_in[0];
  const float* W_edge = (const float*)d_in[1];
  const float* b_edge = (const float*)d_in[2];
  const float* gWih   = (const float*)d_in[3];
  const float* gWhh   = (const float*)d_in[4];
  const float* gbih   = (const float*)d_in[5];
  const float* gbhh   = (const float*)d_in[6];
  const float* lWi0   = (const float*)d_in[7];
  const float* lWh0   = (const float*)d_in[8];
  const float* lbi0   = (const float*)d_in[9];
  const float* lbh0   = (const float*)d_in[10];
  const float* lWi1   = (const float*)d_in[11];
  const float* lWh1   = (const float*)d_in[12];
  const float* lbi1   = (const float*)d_in[13];
  const float* lbh1   = (const float*)d_in[14];
  const float* lWi2   = (const float*)d_in[15];
  const float* lWh2   = (const float*)d_in[16];
  const float* lbi2   = (const float*)d_in[17];
  const float* lbh2   = (const float*)d_in[18];
  const float* Wp     = (const float*)d_in[19];
  const float* bp     = (const float*)d_in[20];
  const int* src      = (const int*)d_in[21];
  const int* dst      = (const int*)d_in[22];
  const int* ety      = (const int*)d_in[23];
  float* out = (float*)d_out;

  char* ws = (char*)d_ws;
  u16* recs    = (u16*)ws;              // 2,048,000 B
  int* rows    = (int*)(ws + 2048000);  //   771,840 B (320 x 3 x 201)
  u16* WeTb    = (u16*)(ws + 2819840);  //    49,152 B
  u16* Wihb    = (u16*)(ws + 2868992);  //    24,576 B
  u16* Whhb    = (u16*)(ws + 2893568);  //    24,576 B
  u16* WTih0b  = (u16*)(ws + 2918144);  //    65,536 B
  u16* WThh0b  = (u16*)(ws + 2983680);  //    32,768 B
  u16* WTih1b  = (u16*)(ws + 3016448);  //    32,768 B
  u16* WThh1b  = (u16*)(ws + 3049216);  //    32,768 B
  u16* WTih2b  = (u16*)(ws + 3081984);  //    32,768 B
  u16* WThh2b  = (u16*)(ws + 3114752);  //    32,768 B

  k_csr<<<NGRAPH, 256, 0, stream>>>(src, dst, ety, recs, rows);
  k_prep<<<640, 256, 0, stream>>>(W_edge, gWih, gWhh, lWi0, lWh0, lWi1, lWh1, lWi2, lWh2,
                                  WeTb, Wihb, Whhb, WTih0b, WThh0b, WTih1b, WThh1b, WTih2b, WThh2b);
  k_ggnn<<<NGRAPH, 512, 0, stream>>>(feats, WeTb, b_edge, Wihb, Whhb, gbih, gbhh, recs, rows,
                                     WTih0b, WThh0b, WTih1b, WThh1b, WTih2b, WThh2b,
                                     lbi0, lbh0, lbi1, lbh1, lbi2, lbh2, Wp, bp, out);
}

// Round 6
// 810.613 us; speedup vs baseline: 1.2632x; 1.1298x over previous
//
#include <hip/hip_runtime.h>

typedef unsigned short u16;
typedef unsigned int u32;

#define DIM 64
#define NGRAPH 320
#define NPG 200
#define EPG 3200
#define NSTEPS 5
#define NITERS 6
#define NTILES 13  // ceil(200/16)
#define NPAD 208   // NTILES*16
#define NTHR 1024  // 16 waves, 4 waves/SIMD

typedef __attribute__((ext_vector_type(8))) short bf16x8;
typedef __attribute__((ext_vector_type(4))) float f32x4;

__device__ __forceinline__ float bf2f(u16 u) {
  u32 x = ((u32)u) << 16;
  float f;
  __builtin_memcpy(&f, &x, 4);
  return f;
}
__device__ __forceinline__ u16 f2bf(float f) {
  u32 x;
  __builtin_memcpy(&x, &f, 4);
  x = (x + 0x7FFFu + ((x >> 16) & 1u)) >> 16;
  return (u16)x;
}
__device__ __forceinline__ float bflo(u32 w) {
  u32 x = w << 16;
  float f;
  __builtin_memcpy(&f, &x, 4);
  return f;
}
__device__ __forceinline__ float bfhi(u32 w) {
  u32 x = w & 0xffff0000u;
  float f;
  __builtin_memcpy(&f, &x, 4);
  return f;
}
__device__ __forceinline__ float sigmf(float x) { return 1.0f / (1.0f + __expf(-x)); }
// XOR swizzle for bf16 [row][64] LDS tiles read as ds_read_b128 at 128B row stride.
__device__ __forceinline__ int swz(int row, int col) { return row * 64 + (col ^ ((row & 7) << 3)); }

// ---------------- prep ----------------

// 3-phase CSR: phase p = etype>>1, local t = etype&1. rec = t*NPG + src (direct wh row id).
__global__ void __launch_bounds__(256) k_csr(const int* __restrict__ src,
                                             const int* __restrict__ dst,
                                             const int* __restrict__ ety,
                                             u16* __restrict__ recs,
                                             int* __restrict__ rows) {
  __shared__ int cnt[3 * NPG];
  __shared__ int rofs[3 * (NPG + 1)];
  int g = blockIdx.x, tid = threadIdx.x;
  int base = g * NPG;
  for (int i = tid; i < 3 * NPG; i += 256) cnt[i] = 0;
  __syncthreads();
  for (int e = tid; e < EPG; e += 256) {
    int d = dst[g * EPG + e] - base;
    int t = ety[g * EPG + e];
    atomicAdd(&cnt[(t >> 1) * NPG + d], 1);
  }
  __syncthreads();
  if (tid == 0) {
    int s = 0;
    for (int p = 0; p < 3; p++) {
      for (int n = 0; n < NPG; n++) {
        rofs[p * (NPG + 1) + n] = s;
        s += cnt[p * NPG + n];
      }
      rofs[p * (NPG + 1) + NPG] = s;
    }
  }
  __syncthreads();
  for (int i = tid; i < 3 * NPG; i += 256) cnt[i] = rofs[(i / NPG) * (NPG + 1) + (i % NPG)];
  __syncthreads();
  for (int e = tid; e < EPG; e += 256) {
    int d = dst[g * EPG + e] - base;
    int t = ety[g * EPG + e];
    int sl = src[g * EPG + e] - base;
    int pos = atomicAdd(&cnt[(t >> 1) * NPG + d], 1);
    recs[g * EPG + pos] = (u16)((t & 1) * NPG + sl);
  }
  for (int i = tid; i < 3 * (NPG + 1); i += 256) rows[g * 3 * (NPG + 1) + i] = rofs[i];
}

// All weight conversions/transposes in ONE launch (163840 elems = 640 x 256).
__global__ void __launch_bounds__(256) k_prep(
    const float* __restrict__ W_edge, const float* __restrict__ gWih, const float* __restrict__ gWhh,
    const float* __restrict__ lWi0, const float* __restrict__ lWh0,
    const float* __restrict__ lWi1, const float* __restrict__ lWh1,
    const float* __restrict__ lWi2, const float* __restrict__ lWh2,
    u16* __restrict__ WeTb, u16* __restrict__ Wihb, u16* __restrict__ Whhb,
    u16* __restrict__ WTih0b, u16* __restrict__ WThh0b,
    u16* __restrict__ WTih1b, u16* __restrict__ WThh1b,
    u16* __restrict__ WTih2b, u16* __restrict__ WThh2b) {
  int i = blockIdx.x * 256 + threadIdx.x;
  if (i < 24576) {  // WeT: [t][o][k] <- W_edge[t][k][o]
    int t = i >> 12, rem = i & 4095, o = rem >> 6, k = rem & 63;
    WeTb[i] = f2bf(W_edge[t * 4096 + k * 64 + o]);
  } else if (i < 36864) {
    int idx = i - 24576;
    Wihb[idx] = f2bf(gWih[idx]);
  } else if (i < 49152) {
    int idx = i - 36864;
    Whhb[idx] = f2bf(gWhh[idx]);
  } else if (i < 81920) {  // WTih0: [k<128][j<256] <- lWi0[j][k]
    int idx = i - 49152;
    int k = idx >> 8, jj = idx & 255;
    WTih0b[idx] = f2bf(lWi0[jj * 128 + k]);
  } else {  // five [k<64][j<256] transposes
    int idx = i - 81920;
    int seg = idx >> 14;
    int r = idx & 16383;
    int k = r >> 8, jj = r & 255;
    const float* sp = seg == 0 ? lWh0 : seg == 1 ? lWi1 : seg == 2 ? lWh1 : seg == 3 ? lWi2 : lWh2;
    u16* dp = seg == 0 ? WThh0b : seg == 1 ? WTih1b : seg == 2 ? WThh1b : seg == 3 ? WTih2b : WThh2b;
    dp[r] = f2bf(sp[jj * 64 + k]);
  }
}

// ---------------- fully fused GGNN + Set2Set: one block = one graph ----------------
// R6: 1024 threads (16 waves, 4 waves/SIMD) — R5 was latency-bound at 2 waves/SIMD
// (VALUBusy 17.7%, stalls ~80%). Set2set split 4-way: 56 weight regs/thread
// (R5's 112 spilled ~22 regs = the 14.7MB WRITE). LDS ~150.5KB -> 1 block/CU.

__global__ void __launch_bounds__(NTHR, 1) k_ggnn(
    const float* __restrict__ feats,
    const u16* __restrict__ WeTb, const float* __restrict__ b_edge,
    const u16* __restrict__ Wihb, const u16* __restrict__ Whhb,
    const float* __restrict__ gbih, const float* __restrict__ gbhh,
    const u16* __restrict__ recs, const int* __restrict__ rows,
    const u16* __restrict__ WTih0b, const u16* __restrict__ WThh0b,
    const u16* __restrict__ WTih1b, const u16* __restrict__ WThh1b,
    const u16* __restrict__ WTih2b, const u16* __restrict__ WThh2b,
    const float* __restrict__ b_ih0, const float* __restrict__ b_hh0,
    const float* __restrict__ b_ih1, const float* __restrict__ b_hh1,
    const float* __restrict__ b_ih2, const float* __restrict__ b_hh2,
    const float* __restrict__ Wp, const float* __restrict__ bp,
    float* __restrict__ out) {
  __shared__ __align__(16) u16 hb_s[NPAD * 64];     // bf16 h (swizzled)       26624B
  __shared__ __align__(16) u16 wh_s[2 * NPG * 64];  // 2-etype Wh / ab alias   51200B
  __shared__ __align__(16) float acc_s[NPG * 64];   // f32 gather acc / feat_s 51200B
  __shared__ __align__(16) u16 rec_s[EPG];          //                          6400B
  __shared__ int rows_s[3 * (NPG + 1)];             //                          2412B
  // set2set scratch (~12.3KB). Total ~150.5KB -> 1 block/CU.
  __shared__ float qstar[128], xbuf[64], hs_s[3][64], cs_s[3][64];
  __shared__ float gates[256], gpart[4 * 256], e_s[NPG], red[16][64], scal[2];

  int g = blockIdx.x, tid = threadIdx.x;
  int lane = tid & 63, wid = tid >> 6;  // 16 waves
  int m = lane & 15, quad = lane >> 4;
  int half = lane >> 5, l32 = lane & 31;

  // ---- stage graph-local state ----
  const float* fg = feats + (size_t)g * (NPG * 64);
  for (int i = tid; i < NPG * 64; i += NTHR) hb_s[swz(i >> 6, i & 63)] = f2bf(fg[i]);
  for (int i = tid; i < (NPAD - NPG) * 64; i += NTHR) hb_s[NPG * 64 + i] = 0;  // pad rows
  {
    const u32* r32 = (const u32*)(recs + (size_t)g * EPG);
    u32* rl = (u32*)rec_s;
    for (int i = tid; i < EPG / 2; i += NTHR) rl[i] = r32[i];
  }
  for (int i = tid; i < 3 * (NPG + 1); i += NTHR) rows_s[i] = rows[g * 3 * (NPG + 1) + i];

  // fp32 h in registers: wave wid owns tile nt=wid (<13); thread owns
  // (node = wid*16+quad*4+r, d = dq*16+m). Static indexing throughout.
  float hreg[4][4] = {};
  if (wid < NTILES) {
#pragma unroll
    for (int r = 0; r < 4; r++) {
      int node = wid * 16 + quad * 4 + r;
      if (node < NPG) {
#pragma unroll
        for (int dq = 0; dq < 4; dq++) hreg[r][dq] = fg[node * 64 + dq * 16 + m];
      }
    }
  }

  u16* ab_s = wh_s;  // alias: wh dead once gathers finish
  int ot = wid & 3, hh = wid >> 2;  // hh in 0..3

#pragma unroll 1
  for (int step = 0; step < NSTEPS; step++) {
    __syncthreads();  // prev GRU done (step>0) / staging done (step 0); acc_s dead
    // ---- zero f32 accumulator ----
    {
      float4* z4 = (float4*)acc_s;
      float4 z = {0.f, 0.f, 0.f, 0.f};
      for (int i = tid; i < NPG * 16; i += NTHR) z4[i] = z;
    }
#pragma unroll 1
    for (int ph = 0; ph < 3; ph++) {
      if (ph > 0) __syncthreads();  // gather of ph-1 done reading wh_s
      // ---- transform etypes {2ph, 2ph+1} -> wh_s; B-fragments hoisted per wave ----
      {
        const u16* bp0 = WeTb + (((2 * ph) * 64 + ot * 16 + m) * 64) + quad * 8;
        const u16* bp1 = WeTb + (((2 * ph + 1) * 64 + ot * 16 + m) * 64) + quad * 8;
        bf16x8 B00 = *(const bf16x8*)bp0;
        bf16x8 B01 = *(const bf16x8*)(bp0 + 32);
        bf16x8 B10 = *(const bf16x8*)bp1;
        bf16x8 B11 = *(const bf16x8*)(bp1 + 32);
        float bias0 = b_edge[(2 * ph) * 64 + ot * 16 + m];
        float bias1 = b_edge[(2 * ph + 1) * 64 + ot * 16 + m];
        for (int nt = hh; nt < NTILES; nt += 4) {  // tl = 0
          int arow = nt * 16 + m;
          bf16x8 a0 = *(const bf16x8*)(hb_s + swz(arow, quad * 8));
          bf16x8 a1 = *(const bf16x8*)(hb_s + swz(arow, quad * 8 + 32));
          f32x4 c = {0.f, 0.f, 0.f, 0.f};
          c = __builtin_amdgcn_mfma_f32_16x16x32_bf16(a0, B00, c, 0, 0, 0);
          c = __builtin_amdgcn_mfma_f32_16x16x32_bf16(a1, B01, c, 0, 0, 0);
#pragma unroll
          for (int r = 0; r < 4; r++) {
            int node = nt * 16 + quad * 4 + r;
            if (node < NPG) wh_s[node * 64 + ot * 16 + m] = f2bf(c[r] + bias0);
          }
        }
        for (int nt = 3 - hh; nt < NTILES; nt += 4) {  // tl = 1 (reversed for balance)
          int arow = nt * 16 + m;
          bf16x8 a0 = *(const bf16x8*)(hb_s + swz(arow, quad * 8));
          bf16x8 a1 = *(const bf16x8*)(hb_s + swz(arow, quad * 8 + 32));
          f32x4 c = {0.f, 0.f, 0.f, 0.f};
          c = __builtin_amdgcn_mfma_f32_16x16x32_bf16(a0, B10, c, 0, 0, 0);
          c = __builtin_amdgcn_mfma_f32_16x16x32_bf16(a1, B11, c, 0, 0, 0);
#pragma unroll
          for (int r = 0; r < 4; r++) {
            int node = nt * 16 + quad * 4 + r;
            if (node < NPG) wh_s[(NPG + node) * 64 + ot * 16 + m] = f2bf(c[r] + bias1);
          }
        }
      }
      __syncthreads();  // wh ready (and, for ph==0, acc zero done)
      // ---- gather: half-wave per edge, u32 (2 cols) per lane; += into acc_s ----
      const int* rowp = rows_s + ph * (NPG + 1);
      for (int q = 0; q < 13; q++) {
        int n = q * 16 + wid;
        if (n >= NPG) continue;  // wave-uniform; no barriers inside
        int rs = rowp[n], re = rowp[n + 1];
        float r0 = 0.f, r1 = 0.f;
        int e = rs;
        for (; e + 4 <= re; e += 4) {
          int pA = rec_s[e + half];
          int pB = rec_s[e + 2 + half];
          u32 wA = *(const u32*)(wh_s + pA * 64 + 2 * l32);
          u32 wB = *(const u32*)(wh_s + pB * 64 + 2 * l32);
          r0 += bflo(wA) + bflo(wB);
          r1 += bfhi(wA) + bfhi(wB);
        }
        if (e + 2 <= re) {
          int pA = rec_s[e + half];
          u32 wA = *(const u32*)(wh_s + pA * 64 + 2 * l32);
          r0 += bflo(wA);
          r1 += bfhi(wA);
          e += 2;
        }
        if (e < re && half == 0) {
          int pA = rec_s[e];
          u32 wA = *(const u32*)(wh_s + pA * 64 + 2 * l32);
          r0 += bflo(wA);
          r1 += bfhi(wA);
        }
        r0 += __shfl_xor(r0, 32);
        r1 += __shfl_xor(r1, 32);
        if (lane < 32) {
          float2* p = (float2*)(acc_s + n * 64 + 2 * l32);
          float2 v = *p;
          v.x += r0;
          v.y += r1;
          *p = v;
        }
      }
    }
    __syncthreads();  // all gathers done; acc_s final; wh_s free -> ab_s
    // ---- convert acc_s -> ab_s (swizzled bf16) ----
    for (int idx = tid; idx < NPG * 32; idx += NTHR) {
      int n = idx >> 5, jj = idx & 31;
      float2 v = *(const float2*)(acc_s + n * 64 + 2 * jj);
      u32 pk = (u32)f2bf(v.x) | ((u32)f2bf(v.y) << 16);
      *(u32*)(ab_s + n * 64 + ((2 * jj) ^ ((n & 7) << 3))) = pk;
    }
    __syncthreads();  // ab ready
    // ---- GRU: wave wid owns tile nt=wid; per-dq fragments (16 acc regs) ----
    if (wid < NTILES) {
      int nt = wid;
      int arow = nt * 16 + m;
      bf16x8 aa0 = *(const bf16x8*)(ab_s + swz(arow, quad * 8));
      bf16x8 aa1 = *(const bf16x8*)(ab_s + swz(arow, quad * 8 + 32));
      bf16x8 ah0 = *(const bf16x8*)(hb_s + swz(arow, quad * 8));
      bf16x8 ah1 = *(const bf16x8*)(hb_s + swz(arow, quad * 8 + 32));
#pragma unroll
      for (int dq = 0; dq < 4; dq++) {
        int d = dq * 16 + m;
        f32x4 z4 = {0.f, 0.f, 0.f, 0.f};
        // r gate (jt = dq): ih + hh chained into one acc
        const u16* bi = Wihb + (dq * 16 + m) * 64 + quad * 8;
        const u16* bh = Whhb + (dq * 16 + m) * 64 + quad * 8;
        f32x4 cr = z4;
        {
          bf16x8 b0 = *(const bf16x8*)bi, b1 = *(const bf16x8*)(bi + 32);
          bf16x8 c0 = *(const bf16x8*)bh, c1 = *(const bf16x8*)(bh + 32);
          cr = __builtin_amdgcn_mfma_f32_16x16x32_bf16(ah0, c0, cr, 0, 0, 0);
          cr = __builtin_amdgcn_mfma_f32_16x16x32_bf16(ah1, c1, cr, 0, 0, 0);
          cr = __builtin_amdgcn_mfma_f32_16x16x32_bf16(aa0, b0, cr, 0, 0, 0);
          cr = __builtin_amdgcn_mfma_f32_16x16x32_bf16(aa1, b1, cr, 0, 0, 0);
        }
        // z gate (jt = 4+dq)
        const u16* bi2 = Wihb + ((4 + dq) * 16 + m) * 64 + quad * 8;
        const u16* bh2 = Whhb + ((4 + dq) * 16 + m) * 64 + quad * 8;
        f32x4 cz = z4;
        {
          bf16x8 b0 = *(const bf16x8*)bi2, b1 = *(const bf16x8*)(bi2 + 32);
          bf16x8 c0 = *(const bf16x8*)bh2, c1 = *(const bf16x8*)(bh2 + 32);
          cz = __builtin_amdgcn_mfma_f32_16x16x32_bf16(ah0, c0, cz, 0, 0, 0);
          cz = __builtin_amdgcn_mfma_f32_16x16x32_bf16(ah1, c1, cz, 0, 0, 0);
          cz = __builtin_amdgcn_mfma_f32_16x16x32_bf16(aa0, b0, cz, 0, 0, 0);
          cz = __builtin_amdgcn_mfma_f32_16x16x32_bf16(aa1, b1, cz, 0, 0, 0);
        }
        // n gate (jt = 8+dq): ih and hh separate
        const u16* bi3 = Wihb + ((8 + dq) * 16 + m) * 64 + quad * 8;
        const u16* bh3 = Whhb + ((8 + dq) * 16 + m) * 64 + quad * 8;
        f32x4 ci = z4, ch = z4;
        {
          bf16x8 b0 = *(const bf16x8*)bi3, b1 = *(const bf16x8*)(bi3 + 32);
          bf16x8 c0 = *(const bf16x8*)bh3, c1 = *(const bf16x8*)(bh3 + 32);
          ci = __builtin_amdgcn_mfma_f32_16x16x32_bf16(aa0, b0, ci, 0, 0, 0);
          ci = __builtin_amdgcn_mfma_f32_16x16x32_bf16(aa1, b1, ci, 0, 0, 0);
          ch = __builtin_amdgcn_mfma_f32_16x16x32_bf16(ah0, c0, ch, 0, 0, 0);
          ch = __builtin_amdgcn_mfma_f32_16x16x32_bf16(ah1, c1, ch, 0, 0, 0);
        }
        float bi_r = gbih[d], bh_r = gbhh[d];
        float bi_z = gbih[64 + d], bh_z = gbhh[64 + d];
        float bi_n = gbih[128 + d], bh_n = gbhh[128 + d];
#pragma unroll
        for (int r = 0; r < 4; r++) {
          int node = nt * 16 + quad * 4 + r;
          if (node < NPG) {
            float rr = sigmf(cr[r] + bi_r + bh_r);
            float zz = sigmf(cz[r] + bi_z + bh_z);
            float nn = tanhf(ci[r] + bi_n + rr * (ch[r] + bh_n));
            float hv = hreg[r][dq];
            float hnew = (1.0f - zz) * nn + zz * hv;
            hreg[r][dq] = hnew;
            hb_s[swz(node, d)] = f2bf(hnew);
            if (step == NSTEPS - 1) acc_s[node * 64 + d] = hnew;  // feat_s for set2set
          }
        }
      }
    }
  }
  __syncthreads();  // final h (feat_s = acc_s) ready
  const float* feat_s = acc_s;

  // ================= Set2Set: 4-part matvec, weights register-resident =================
  // Layer0 K=192 (qstar 128 | hs0 64) -> 4 parts x 48. Layers 1,2 K=128 -> 4 x 32.
  int j = tid & 255, part = tid >> 8;  // wave-uniform part in 0..3
  u32 w0[24], w1[16], w2[16];
  if (part == 0) {
#pragma unroll
    for (int kk = 0; kk < 24; kk++)
      w0[kk] = (u32)WTih0b[(2 * kk) * 256 + j] | ((u32)WTih0b[(2 * kk + 1) * 256 + j] << 16);
  } else if (part == 1) {
#pragma unroll
    for (int kk = 0; kk < 24; kk++)
      w0[kk] = (u32)WTih0b[(48 + 2 * kk) * 256 + j] | ((u32)WTih0b[(49 + 2 * kk) * 256 + j] << 16);
  } else if (part == 2) {
#pragma unroll
    for (int kk = 0; kk < 16; kk++)
      w0[kk] = (u32)WTih0b[(96 + 2 * kk) * 256 + j] | ((u32)WTih0b[(97 + 2 * kk) * 256 + j] << 16);
#pragma unroll
    for (int kk = 0; kk < 8; kk++)
      w0[16 + kk] = (u32)WThh0b[(2 * kk) * 256 + j] | ((u32)WThh0b[(2 * kk + 1) * 256 + j] << 16);
  } else {
#pragma unroll
    for (int kk = 0; kk < 24; kk++)
      w0[kk] = (u32)WThh0b[(16 + 2 * kk) * 256 + j] | ((u32)WThh0b[(17 + 2 * kk) * 256 + j] << 16);
  }
  {
    const u16* W1 = (part < 2) ? WTih1b : WThh1b;
    const u16* W2 = (part < 2) ? WTih2b : WThh2b;
    int ko = (part & 1) * 32;
#pragma unroll
    for (int kk = 0; kk < 16; kk++) {
      w1[kk] = (u32)W1[(ko + 2 * kk) * 256 + j] | ((u32)W1[(ko + 2 * kk + 1) * 256 + j] << 16);
      w2[kk] = (u32)W2[(ko + 2 * kk) * 256 + j] | ((u32)W2[(ko + 2 * kk + 1) * 256 + j] << 16);
    }
  }
  float bs0 = 0.f, bs1 = 0.f, bs2 = 0.f;
  if (tid < 256) {
    bs0 = b_ih0[tid] + b_hh0[tid];
    bs1 = b_ih1[tid] + b_hh1[tid];
    bs2 = b_ih2[tid] + b_hh2[tid];
  }
  if (tid < 128) qstar[tid] = 0.f;
  if (tid < 64) {
    xbuf[tid] = 0.f;
    for (int l = 0; l < 3; l++) {
      hs_s[l][tid] = 0.f;
      cs_s[l][tid] = 0.f;
    }
  }
  __syncthreads();
#pragma unroll 1
  for (int it = 0; it < NITERS; it++) {
    // ---- layer 0 ----
    {
      float a0 = 0.f, a1 = 0.f;
      if (part == 0) {
#pragma unroll
        for (int kk = 0; kk < 24; kk++) {
          u32 w = w0[kk];
          a0 += qstar[2 * kk] * bflo(w);
          a1 += qstar[2 * kk + 1] * bfhi(w);
        }
      } else if (part == 1) {
#pragma unroll
        for (int kk = 0; kk < 24; kk++) {
          u32 w = w0[kk];
          a0 += qstar[48 + 2 * kk] * bflo(w);
          a1 += qstar[49 + 2 * kk] * bfhi(w);
        }
      } else if (part == 2) {
#pragma unroll
        for (int kk = 0; kk < 16; kk++) {
          u32 w = w0[kk];
          a0 += qstar[96 + 2 * kk] * bflo(w);
          a1 += qstar[97 + 2 * kk] * bfhi(w);
        }
#pragma unroll
        for (int kk = 0; kk < 8; kk++) {
          u32 w = w0[16 + kk];
          a0 += hs_s[0][2 * kk] * bflo(w);
          a1 += hs_s[0][2 * kk + 1] * bfhi(w);
        }
      } else {
#pragma unroll
        for (int kk = 0; kk < 24; kk++) {
          u32 w = w0[kk];
          a0 += hs_s[0][16 + 2 * kk] * bflo(w);
          a1 += hs_s[0][17 + 2 * kk] * bfhi(w);
        }
      }
      gpart[part * 256 + j] = a0 + a1;
    }
    __syncthreads();
    if (tid < 256)
      gates[tid] = gpart[tid] + gpart[256 + tid] + gpart[512 + tid] + gpart[768 + tid] + bs0;
    __syncthreads();
    if (tid < 64) {
      float cc = sigmf(gates[64 + tid]) * cs_s[0][tid] + sigmf(gates[tid]) * tanhf(gates[128 + tid]);
      float x = sigmf(gates[192 + tid]) * tanhf(cc);
      cs_s[0][tid] = cc;
      hs_s[0][tid] = x;
      xbuf[tid] = x;
    }
    __syncthreads();
    // ---- layers 1,2 ----
#pragma unroll 1
    for (int l = 1; l < 3; l++) {
      const u32* wl = (l == 1) ? w1 : w2;
      const float* xv = (part < 2) ? xbuf : hs_s[l];
      int xo = (part & 1) * 32;
      float a0 = 0.f, a1 = 0.f;
#pragma unroll
      for (int kk = 0; kk < 16; kk++) {
        u32 w = wl[kk];
        a0 += xv[xo + 2 * kk] * bflo(w);
        a1 += xv[xo + 2 * kk + 1] * bfhi(w);
      }
      gpart[part * 256 + j] = a0 + a1;
      __syncthreads();
      float bsl = (l == 1) ? bs1 : bs2;
      if (tid < 256)
        gates[tid] = gpart[tid] + gpart[256 + tid] + gpart[512 + tid] + gpart[768 + tid] + bsl;
      __syncthreads();
      if (tid < 64) {
        float cc = sigmf(gates[64 + tid]) * cs_s[l][tid] + sigmf(gates[tid]) * tanhf(gates[128 + tid]);
        float x = sigmf(gates[192 + tid]) * tanhf(cc);
        cs_s[l][tid] = cc;
        hs_s[l][tid] = x;
        xbuf[tid] = x;
      }
      __syncthreads();
    }
    // ---- attention over this graph's nodes ----
    for (int n = wid; n < NPG; n += 16) {
      float v = feat_s[n * 64 + lane] * xbuf[lane];
      for (int off = 32; off > 0; off >>= 1) v += __shfl_down(v, off);
      if (lane == 0) e_s[n] = v;
    }
    __syncthreads();
    if (tid < 64) {
      float mx = -1e30f;
      for (int n = lane; n < NPG; n += 64) mx = fmaxf(mx, e_s[n]);
      for (int off = 32; off > 0; off >>= 1) mx = fmaxf(mx, __shfl_down(mx, off));
      mx = __shfl(mx, 0);
      float ssum = 0.f;
      for (int n = lane; n < NPG; n += 64) {
        float ex = __expf(e_s[n] - mx);
        e_s[n] = ex;
        ssum += ex;
      }
      for (int off = 32; off > 0; off >>= 1) ssum += __shfl_down(ssum, off);
      if (lane == 0) scal[0] = ssum;
    }
    __syncthreads();
    float denom = scal[0];
    {
      float r = 0.f;
      for (int n = wid; n < NPG; n += 16) r += feat_s[n * 64 + lane] * e_s[n];
      red[wid][lane] = r;
    }
    __syncthreads();
    if (tid < 64) {
      float ro = 0.f;
#pragma unroll
      for (int ww = 0; ww < 16; ww++) ro += red[ww][lane];
      qstar[lane] = xbuf[lane];
      qstar[64 + lane] = ro / denom;
    }
    __syncthreads();
  }
  if (tid < 3) {
    float s = bp[tid];
    for (int k = 0; k < 128; k++) s += qstar[k] * Wp[tid * 128 + k];
    out[g * 3 + tid] = s;
  }
}

// ---------------- host ----------------

extern "C" void kernel_launch(void* const* d_in, const int* in_sizes, int n_in,
                              void* d_out, int out_size, void* d_ws, size_t ws_size,
                              hipStream_t stream) {
  const float* feats  = (const float*)d_in[0];
  const float* W_edge = (const float*)d_in[1];
  const float* b_edge = (const float*)d_in[2];
  const float* gWih   = (const float*)d_in[3];
  const float* gWhh   = (const float*)d_in[4];
  const float* gbih   = (const float*)d_in[5];
  const float* gbhh   = (const float*)d_in[6];
  const float* lWi0   = (const float*)d_in[7];
  const float* lWh0   = (const float*)d_in[8];
  const float* lbi0   = (const float*)d_in[9];
  const float* lbh0   = (const float*)d_in[10];
  const float* lWi1   = (const float*)d_in[11];
  const float* lWh1   = (const float*)d_in[12];
  const float* lbi1   = (const float*)d_in[13];
  const float* lbh1   = (const float*)d_in[14];
  const float* lWi2   = (const float*)d_in[15];
  const float* lWh2   = (const float*)d_in[16];
  const float* lbi2   = (const float*)d_in[17];
  const float* lbh2   = (const float*)d_in[18];
  const float* Wp     = (const float*)d_in[19];
  const float* bp     = (const float*)d_in[20];
  const int* src      = (const int*)d_in[21];
  const int* dst      = (const int*)d_in[22];
  const int* ety      = (const int*)d_in[23];
  float* out = (float*)d_out;

  char* ws = (char*)d_ws;
  u16* recs    = (u16*)ws;              // 2,048,000 B
  int* rows    = (int*)(ws + 2048000);  //   771,840 B (320 x 3 x 201)
  u16* WeTb    = (u16*)(ws + 2819840);  //    49,152 B
  u16* Wihb    = (u16*)(ws + 2868992);  //    24,576 B
  u16* Whhb    = (u16*)(ws + 2893568);  //    24,576 B
  u16* WTih0b  = (u16*)(ws + 2918144);  //    65,536 B
  u16* WThh0b  = (u16*)(ws + 2983680);  //    32,768 B
  u16* WTih1b  = (u16*)(ws + 3016448);  //    32,768 B
  u16* WThh1b  = (u16*)(ws + 3049216);  //    32,768 B
  u16* WTih2b  = (u16*)(ws + 3081984);  //    32,768 B
  u16* WThh2b  = (u16*)(ws + 3114752);  //    32,768 B

  k_csr<<<NGRAPH, 256, 0, stream>>>(src, dst, ety, recs, rows);
  k_prep<<<640, 256, 0, stream>>>(W_edge, gWih, gWhh, lWi0, lWh0, lWi1, lWh1, lWi2, lWh2,
                                  WeTb, Wihb, Whhb, WTih0b, WThh0b, WTih1b, WThh1b, WTih2b, WThh2b);
  k_ggnn<<<NGRAPH, NTHR, 0, stream>>>(feats, WeTb, b_edge, Wihb, Whhb, gbih, gbhh, recs, rows,
                                      WTih0b, WThh0b, WTih1b, WThh1b, WTih2b, WThh2b,
                                      lbi0, lbh0, lbi1, lbh1, lbi2, lbh2, Wp, bp, out);
}

// Round 7
// 808.662 us; speedup vs baseline: 1.2662x; 1.0024x over previous
//
#include <hip/hip_runtime.h>

typedef unsigned short u16;
typedef unsigned int u32;

#define DIM 64
#define NGRAPH 320
#define NPG 200
#define EPG 3200
#define NSTEPS 5
#define NITERS 6
#define NTILES 13  // ceil(200/16)
#define NPAD 208   // NTILES*16
#define NTHR 1024  // 16 waves, 4 waves/SIMD

typedef __attribute__((ext_vector_type(8))) short bf16x8;
typedef __attribute__((ext_vector_type(4))) float f32x4;

__device__ __forceinline__ float bf2f(u16 u) {
  u32 x = ((u32)u) << 16;
  float f;
  __builtin_memcpy(&f, &x, 4);
  return f;
}
__device__ __forceinline__ u16 f2bf(float f) {
  u32 x;
  __builtin_memcpy(&x, &f, 4);
  x = (x + 0x7FFFu + ((x >> 16) & 1u)) >> 16;
  return (u16)x;
}
__device__ __forceinline__ float bflo(u32 w) {
  u32 x = w << 16;
  float f;
  __builtin_memcpy(&f, &x, 4);
  return f;
}
__device__ __forceinline__ float bfhi(u32 w) {
  u32 x = w & 0xffff0000u;
  float f;
  __builtin_memcpy(&f, &x, 4);
  return f;
}
__device__ __forceinline__ float sigmf(float x) { return 1.0f / (1.0f + __expf(-x)); }
// XOR swizzle for bf16 [row][64] LDS tiles read as ds_read_b128 at 128B row stride.
__device__ __forceinline__ int swz(int row, int col) { return row * 64 + (col ^ ((row & 7) << 3)); }

// ---------------- prep ----------------

// 3-phase CSR: phase p = etype>>1, local t = etype&1. rec = t*NPG + src (direct wh row id).
__global__ void __launch_bounds__(256) k_csr(const int* __restrict__ src,
                                             const int* __restrict__ dst,
                                             const int* __restrict__ ety,
                                             u16* __restrict__ recs,
                                             int* __restrict__ rows) {
  __shared__ int cnt[3 * NPG];
  __shared__ int rofs[3 * (NPG + 1)];
  int g = blockIdx.x, tid = threadIdx.x;
  int base = g * NPG;
  for (int i = tid; i < 3 * NPG; i += 256) cnt[i] = 0;
  __syncthreads();
  for (int e = tid; e < EPG; e += 256) {
    int d = dst[g * EPG + e] - base;
    int t = ety[g * EPG + e];
    atomicAdd(&cnt[(t >> 1) * NPG + d], 1);
  }
  __syncthreads();
  if (tid == 0) {
    int s = 0;
    for (int p = 0; p < 3; p++) {
      for (int n = 0; n < NPG; n++) {
        rofs[p * (NPG + 1) + n] = s;
        s += cnt[p * NPG + n];
      }
      rofs[p * (NPG + 1) + NPG] = s;
    }
  }
  __syncthreads();
  for (int i = tid; i < 3 * NPG; i += 256) cnt[i] = rofs[(i / NPG) * (NPG + 1) + (i % NPG)];
  __syncthreads();
  for (int e = tid; e < EPG; e += 256) {
    int d = dst[g * EPG + e] - base;
    int t = ety[g * EPG + e];
    int sl = src[g * EPG + e] - base;
    int pos = atomicAdd(&cnt[(t >> 1) * NPG + d], 1);
    recs[g * EPG + pos] = (u16)((t & 1) * NPG + sl);
  }
  for (int i = tid; i < 3 * (NPG + 1); i += 256) rows[g * 3 * (NPG + 1) + i] = rofs[i];
}

// All weight conversions/transposes in ONE launch (163840 elems = 640 x 256).
__global__ void __launch_bounds__(256) k_prep(
    const float* __restrict__ W_edge, const float* __restrict__ gWih, const float* __restrict__ gWhh,
    const float* __restrict__ lWi0, const float* __restrict__ lWh0,
    const float* __restrict__ lWi1, const float* __restrict__ lWh1,
    const float* __restrict__ lWi2, const float* __restrict__ lWh2,
    u16* __restrict__ WeTb, u16* __restrict__ Wihb, u16* __restrict__ Whhb,
    u16* __restrict__ WTih0b, u16* __restrict__ WThh0b,
    u16* __restrict__ WTih1b, u16* __restrict__ WThh1b,
    u16* __restrict__ WTih2b, u16* __restrict__ WThh2b) {
  int i = blockIdx.x * 256 + threadIdx.x;
  if (i < 24576) {  // WeT: [t][o][k] <- W_edge[t][k][o]
    int t = i >> 12, rem = i & 4095, o = rem >> 6, k = rem & 63;
    WeTb[i] = f2bf(W_edge[t * 4096 + k * 64 + o]);
  } else if (i < 36864) {
    int idx = i - 24576;
    Wihb[idx] = f2bf(gWih[idx]);
  } else if (i < 49152) {
    int idx = i - 36864;
    Whhb[idx] = f2bf(gWhh[idx]);
  } else if (i < 81920) {  // WTih0: [k<128][j<256] <- lWi0[j][k]
    int idx = i - 49152;
    int k = idx >> 8, jj = idx & 255;
    WTih0b[idx] = f2bf(lWi0[jj * 128 + k]);
  } else {  // five [k<64][j<256] transposes
    int idx = i - 81920;
    int seg = idx >> 14;
    int r = idx & 16383;
    int k = r >> 8, jj = r & 255;
    const float* sp = seg == 0 ? lWh0 : seg == 1 ? lWi1 : seg == 2 ? lWh1 : seg == 3 ? lWi2 : lWh2;
    u16* dp = seg == 0 ? WThh0b : seg == 1 ? WTih1b : seg == 2 ? WThh1b : seg == 3 ? WTih2b : WThh2b;
    dp[r] = f2bf(sp[jj * 64 + k]);
  }
}

// ---------------- fully fused GGNN + Set2Set: one block = one graph ----------------
// R7: __launch_bounds__(1024, 4) — min 4 waves/EU (= what LDS forces anyway) raises
// the VGPR cap to 512/4 = 128 (R6's default heuristic targeted 8 waves/EU -> 64 VGPR
// -> re-spilled 88MB). Set2set weights now read from global (L2-resident, 229KB shared
// by all blocks) — no per-thread weight arrays to spill regardless of the cap.

__global__ void __launch_bounds__(NTHR, 4) k_ggnn(
    const float* __restrict__ feats,
    const u16* __restrict__ WeTb, const float* __restrict__ b_edge,
    const u16* __restrict__ Wihb, const u16* __restrict__ Whhb,
    const float* __restrict__ gbih, const float* __restrict__ gbhh,
    const u16* __restrict__ recs, const int* __restrict__ rows,
    const u16* __restrict__ WTih0b, const u16* __restrict__ WThh0b,
    const u16* __restrict__ WTih1b, const u16* __restrict__ WThh1b,
    const u16* __restrict__ WTih2b, const u16* __restrict__ WThh2b,
    const float* __restrict__ b_ih0, const float* __restrict__ b_hh0,
    const float* __restrict__ b_ih1, const float* __restrict__ b_hh1,
    const float* __restrict__ b_ih2, const float* __restrict__ b_hh2,
    const float* __restrict__ Wp, const float* __restrict__ bp,
    float* __restrict__ out) {
  __shared__ __align__(16) u16 hb_s[NPAD * 64];     // bf16 h (swizzled)       26624B
  __shared__ __align__(16) u16 wh_s[2 * NPG * 64];  // 2-etype Wh / ab alias   51200B
  __shared__ __align__(16) float acc_s[NPG * 64];   // f32 gather acc / feat_s 51200B
  __shared__ __align__(16) u16 rec_s[EPG];          //                          6400B
  __shared__ int rows_s[3 * (NPG + 1)];             //                          2412B
  // set2set scratch (~12.3KB). Total ~150.5KB -> 1 block/CU.
  __shared__ float qstar[128], xbuf[64], hs_s[3][64], cs_s[3][64];
  __shared__ float gates[256], gpart[4 * 256], e_s[NPG], red[16][64], scal[2];

  int g = blockIdx.x, tid = threadIdx.x;
  int lane = tid & 63, wid = tid >> 6;  // 16 waves
  int m = lane & 15, quad = lane >> 4;
  int half = lane >> 5, l32 = lane & 31;

  // ---- stage graph-local state ----
  const float* fg = feats + (size_t)g * (NPG * 64);
  for (int i = tid; i < NPG * 64; i += NTHR) hb_s[swz(i >> 6, i & 63)] = f2bf(fg[i]);
  for (int i = tid; i < (NPAD - NPG) * 64; i += NTHR) hb_s[NPG * 64 + i] = 0;  // pad rows
  {
    const u32* r32 = (const u32*)(recs + (size_t)g * EPG);
    u32* rl = (u32*)rec_s;
    for (int i = tid; i < EPG / 2; i += NTHR) rl[i] = r32[i];
  }
  for (int i = tid; i < 3 * (NPG + 1); i += NTHR) rows_s[i] = rows[g * 3 * (NPG + 1) + i];

  // fp32 h in registers: wave wid owns tile nt=wid (<13); thread owns
  // (node = wid*16+quad*4+r, d = dq*16+m). Static indexing throughout.
  float hreg[4][4] = {};
  if (wid < NTILES) {
#pragma unroll
    for (int r = 0; r < 4; r++) {
      int node = wid * 16 + quad * 4 + r;
      if (node < NPG) {
#pragma unroll
        for (int dq = 0; dq < 4; dq++) hreg[r][dq] = fg[node * 64 + dq * 16 + m];
      }
    }
  }

  u16* ab_s = wh_s;  // alias: wh dead once gathers finish
  int ot = wid & 3, hh = wid >> 2;  // hh in 0..3

#pragma unroll 1
  for (int step = 0; step < NSTEPS; step++) {
    __syncthreads();  // prev GRU done (step>0) / staging done (step 0); acc_s dead
    // ---- zero f32 accumulator ----
    {
      float4* z4 = (float4*)acc_s;
      float4 z = {0.f, 0.f, 0.f, 0.f};
      for (int i = tid; i < NPG * 16; i += NTHR) z4[i] = z;
    }
#pragma unroll 1
    for (int ph = 0; ph < 3; ph++) {
      if (ph > 0) __syncthreads();  // gather of ph-1 done reading wh_s
      // ---- transform etypes {2ph, 2ph+1} -> wh_s; B-fragments hoisted per wave ----
      {
        const u16* bp0 = WeTb + (((2 * ph) * 64 + ot * 16 + m) * 64) + quad * 8;
        const u16* bp1 = WeTb + (((2 * ph + 1) * 64 + ot * 16 + m) * 64) + quad * 8;
        bf16x8 B00 = *(const bf16x8*)bp0;
        bf16x8 B01 = *(const bf16x8*)(bp0 + 32);
        bf16x8 B10 = *(const bf16x8*)bp1;
        bf16x8 B11 = *(const bf16x8*)(bp1 + 32);
        float bias0 = b_edge[(2 * ph) * 64 + ot * 16 + m];
        float bias1 = b_edge[(2 * ph + 1) * 64 + ot * 16 + m];
        for (int nt = hh; nt < NTILES; nt += 4) {  // tl = 0
          int arow = nt * 16 + m;
          bf16x8 a0 = *(const bf16x8*)(hb_s + swz(arow, quad * 8));
          bf16x8 a1 = *(const bf16x8*)(hb_s + swz(arow, quad * 8 + 32));
          f32x4 c = {0.f, 0.f, 0.f, 0.f};
          c = __builtin_amdgcn_mfma_f32_16x16x32_bf16(a0, B00, c, 0, 0, 0);
          c = __builtin_amdgcn_mfma_f32_16x16x32_bf16(a1, B01, c, 0, 0, 0);
#pragma unroll
          for (int r = 0; r < 4; r++) {
            int node = nt * 16 + quad * 4 + r;
            if (node < NPG) wh_s[node * 64 + ot * 16 + m] = f2bf(c[r] + bias0);
          }
        }
        for (int nt = 3 - hh; nt < NTILES; nt += 4) {  // tl = 1 (reversed for balance)
          int arow = nt * 16 + m;
          bf16x8 a0 = *(const bf16x8*)(hb_s + swz(arow, quad * 8));
          bf16x8 a1 = *(const bf16x8*)(hb_s + swz(arow, quad * 8 + 32));
          f32x4 c = {0.f, 0.f, 0.f, 0.f};
          c = __builtin_amdgcn_mfma_f32_16x16x32_bf16(a0, B10, c, 0, 0, 0);
          c = __builtin_amdgcn_mfma_f32_16x16x32_bf16(a1, B11, c, 0, 0, 0);
#pragma unroll
          for (int r = 0; r < 4; r++) {
            int node = nt * 16 + quad * 4 + r;
            if (node < NPG) wh_s[(NPG + node) * 64 + ot * 16 + m] = f2bf(c[r] + bias1);
          }
        }
      }
      __syncthreads();  // wh ready (and, for ph==0, acc zero done)
      // ---- gather: half-wave per edge, u32 (2 cols) per lane; += into acc_s ----
      const int* rowp = rows_s + ph * (NPG + 1);
      for (int q = 0; q < 13; q++) {
        int n = q * 16 + wid;
        if (n >= NPG) continue;  // wave-uniform; no barriers inside
        int rs = rowp[n], re = rowp[n + 1];
        float r0 = 0.f, r1 = 0.f;
        int e = rs;
        for (; e + 4 <= re; e += 4) {
          int pA = rec_s[e + half];
          int pB = rec_s[e + 2 + half];
          u32 wA = *(const u32*)(wh_s + pA * 64 + 2 * l32);
          u32 wB = *(const u32*)(wh_s + pB * 64 + 2 * l32);
          r0 += bflo(wA) + bflo(wB);
          r1 += bfhi(wA) + bfhi(wB);
        }
        if (e + 2 <= re) {
          int pA = rec_s[e + half];
          u32 wA = *(const u32*)(wh_s + pA * 64 + 2 * l32);
          r0 += bflo(wA);
          r1 += bfhi(wA);
          e += 2;
        }
        if (e < re && half == 0) {
          int pA = rec_s[e];
          u32 wA = *(const u32*)(wh_s + pA * 64 + 2 * l32);
          r0 += bflo(wA);
          r1 += bfhi(wA);
        }
        r0 += __shfl_xor(r0, 32);
        r1 += __shfl_xor(r1, 32);
        if (lane < 32) {
          float2* p = (float2*)(acc_s + n * 64 + 2 * l32);
          float2 v = *p;
          v.x += r0;
          v.y += r1;
          *p = v;
        }
      }
    }
    __syncthreads();  // all gathers done; acc_s final; wh_s free -> ab_s
    // ---- convert acc_s -> ab_s (swizzled bf16) ----
    for (int idx = tid; idx < NPG * 32; idx += NTHR) {
      int n = idx >> 5, jj = idx & 31;
      float2 v = *(const float2*)(acc_s + n * 64 + 2 * jj);
      u32 pk = (u32)f2bf(v.x) | ((u32)f2bf(v.y) << 16);
      *(u32*)(ab_s + n * 64 + ((2 * jj) ^ ((n & 7) << 3))) = pk;
    }
    __syncthreads();  // ab ready
    // ---- GRU: wave wid owns tile nt=wid; per-dq fragments (16 acc regs) ----
    if (wid < NTILES) {
      int nt = wid;
      int arow = nt * 16 + m;
      bf16x8 aa0 = *(const bf16x8*)(ab_s + swz(arow, quad * 8));
      bf16x8 aa1 = *(const bf16x8*)(ab_s + swz(arow, quad * 8 + 32));
      bf16x8 ah0 = *(const bf16x8*)(hb_s + swz(arow, quad * 8));
      bf16x8 ah1 = *(const bf16x8*)(hb_s + swz(arow, quad * 8 + 32));
#pragma unroll
      for (int dq = 0; dq < 4; dq++) {
        int d = dq * 16 + m;
        f32x4 z4 = {0.f, 0.f, 0.f, 0.f};
        // r gate (jt = dq): ih + hh chained into one acc
        const u16* bi = Wihb + (dq * 16 + m) * 64 + quad * 8;
        const u16* bh = Whhb + (dq * 16 + m) * 64 + quad * 8;
        f32x4 cr = z4;
        {
          bf16x8 b0 = *(const bf16x8*)bi, b1 = *(const bf16x8*)(bi + 32);
          bf16x8 c0 = *(const bf16x8*)bh, c1 = *(const bf16x8*)(bh + 32);
          cr = __builtin_amdgcn_mfma_f32_16x16x32_bf16(ah0, c0, cr, 0, 0, 0);
          cr = __builtin_amdgcn_mfma_f32_16x16x32_bf16(ah1, c1, cr, 0, 0, 0);
          cr = __builtin_amdgcn_mfma_f32_16x16x32_bf16(aa0, b0, cr, 0, 0, 0);
          cr = __builtin_amdgcn_mfma_f32_16x16x32_bf16(aa1, b1, cr, 0, 0, 0);
        }
        // z gate (jt = 4+dq)
        const u16* bi2 = Wihb + ((4 + dq) * 16 + m) * 64 + quad * 8;
        const u16* bh2 = Whhb + ((4 + dq) * 16 + m) * 64 + quad * 8;
        f32x4 cz = z4;
        {
          bf16x8 b0 = *(const bf16x8*)bi2, b1 = *(const bf16x8*)(bi2 + 32);
          bf16x8 c0 = *(const bf16x8*)bh2, c1 = *(const bf16x8*)(bh2 + 32);
          cz = __builtin_amdgcn_mfma_f32_16x16x32_bf16(ah0, c0, cz, 0, 0, 0);
          cz = __builtin_amdgcn_mfma_f32_16x16x32_bf16(ah1, c1, cz, 0, 0, 0);
          cz = __builtin_amdgcn_mfma_f32_16x16x32_bf16(aa0, b0, cz, 0, 0, 0);
          cz = __builtin_amdgcn_mfma_f32_16x16x32_bf16(aa1, b1, cz, 0, 0, 0);
        }
        // n gate (jt = 8+dq): ih and hh separate
        const u16* bi3 = Wihb + ((8 + dq) * 16 + m) * 64 + quad * 8;
        const u16* bh3 = Whhb + ((8 + dq) * 16 + m) * 64 + quad * 8;
        f32x4 ci = z4, ch = z4;
        {
          bf16x8 b0 = *(const bf16x8*)bi3, b1 = *(const bf16x8*)(bi3 + 32);
          bf16x8 c0 = *(const bf16x8*)bh3, c1 = *(const bf16x8*)(bh3 + 32);
          ci = __builtin_amdgcn_mfma_f32_16x16x32_bf16(aa0, b0, ci, 0, 0, 0);
          ci = __builtin_amdgcn_mfma_f32_16x16x32_bf16(aa1, b1, ci, 0, 0, 0);
          ch = __builtin_amdgcn_mfma_f32_16x16x32_bf16(ah0, c0, ch, 0, 0, 0);
          ch = __builtin_amdgcn_mfma_f32_16x16x32_bf16(ah1, c1, ch, 0, 0, 0);
        }
        float bi_r = gbih[d], bh_r = gbhh[d];
        float bi_z = gbih[64 + d], bh_z = gbhh[64 + d];
        float bi_n = gbih[128 + d], bh_n = gbhh[128 + d];
#pragma unroll
        for (int r = 0; r < 4; r++) {
          int node = nt * 16 + quad * 4 + r;
          if (node < NPG) {
            float rr = sigmf(cr[r] + bi_r + bh_r);
            float zz = sigmf(cz[r] + bi_z + bh_z);
            float nn = tanhf(ci[r] + bi_n + rr * (ch[r] + bh_n));
            float hv = hreg[r][dq];
            float hnew = (1.0f - zz) * nn + zz * hv;
            hreg[r][dq] = hnew;
            hb_s[swz(node, d)] = f2bf(hnew);
            if (step == NSTEPS - 1) acc_s[node * 64 + d] = hnew;  // feat_s for set2set
          }
        }
      }
    }
  }
  __syncthreads();  // final h (feat_s = acc_s) ready
  const float* feat_s = acc_s;

  // ================= Set2Set: 4-part matvec, weights streamed from L2 =================
  // Layer0 K=192 (qstar 128 | hs0 64) -> parts {0..47, 48..95, 96..127+hs0[0..15],
  // hs0[16..63]}. Layers 1,2 K=128 -> {Wi lo, Wi hi, Wh lo, Wh hi}.
  int j = tid & 255, part = tid >> 8;  // wave-uniform part in 0..3
  float bs0 = 0.f, bs1 = 0.f, bs2 = 0.f;
  if (tid < 256) {
    bs0 = b_ih0[tid] + b_hh0[tid];
    bs1 = b_ih1[tid] + b_hh1[tid];
    bs2 = b_ih2[tid] + b_hh2[tid];
  }
  if (tid < 128) qstar[tid] = 0.f;
  if (tid < 64) {
    xbuf[tid] = 0.f;
    for (int l = 0; l < 3; l++) {
      hs_s[l][tid] = 0.f;
      cs_s[l][tid] = 0.f;
    }
  }
  __syncthreads();
#pragma unroll 1
  for (int it = 0; it < NITERS; it++) {
    // ---- layer 0 ----
    {
      float a0 = 0.f;
      if (part == 0) {
#pragma unroll 8
        for (int k = 0; k < 48; k++) a0 += qstar[k] * bf2f(WTih0b[k * 256 + j]);
      } else if (part == 1) {
#pragma unroll 8
        for (int k = 48; k < 96; k++) a0 += qstar[k] * bf2f(WTih0b[k * 256 + j]);
      } else if (part == 2) {
#pragma unroll 8
        for (int k = 96; k < 128; k++) a0 += qstar[k] * bf2f(WTih0b[k * 256 + j]);
#pragma unroll 8
        for (int k = 0; k < 16; k++) a0 += hs_s[0][k] * bf2f(WThh0b[k * 256 + j]);
      } else {
#pragma unroll 8
        for (int k = 16; k < 64; k++) a0 += hs_s[0][k] * bf2f(WThh0b[k * 256 + j]);
      }
      gpart[part * 256 + j] = a0;
    }
    __syncthreads();
    if (tid < 256)
      gates[tid] = gpart[tid] + gpart[256 + tid] + gpart[512 + tid] + gpart[768 + tid] + bs0;
    __syncthreads();
    if (tid < 64) {
      float cc = sigmf(gates[64 + tid]) * cs_s[0][tid] + sigmf(gates[tid]) * tanhf(gates[128 + tid]);
      float x = sigmf(gates[192 + tid]) * tanhf(cc);
      cs_s[0][tid] = cc;
      hs_s[0][tid] = x;
      xbuf[tid] = x;
    }
    __syncthreads();
    // ---- layers 1,2 ----
#pragma unroll 1
    for (int l = 1; l < 3; l++) {
      const u16* W = (l == 1) ? ((part < 2) ? WTih1b : WThh1b)
                              : ((part < 2) ? WTih2b : WThh2b);
      const float* xv = (part < 2) ? xbuf : hs_s[l];
      int k0 = (part & 1) * 32;
      float a0 = 0.f;
#pragma unroll 8
      for (int k = k0; k < k0 + 32; k++) a0 += xv[k] * bf2f(W[k * 256 + j]);
      gpart[part * 256 + j] = a0;
      __syncthreads();
      float bsl = (l == 1) ? bs1 : bs2;
      if (tid < 256)
        gates[tid] = gpart[tid] + gpart[256 + tid] + gpart[512 + tid] + gpart[768 + tid] + bsl;
      __syncthreads();
      if (tid < 64) {
        float cc = sigmf(gates[64 + tid]) * cs_s[l][tid] + sigmf(gates[tid]) * tanhf(gates[128 + tid]);
        float x = sigmf(gates[192 + tid]) * tanhf(cc);
        cs_s[l][tid] = cc;
        hs_s[l][tid] = x;
        xbuf[tid] = x;
      }
      __syncthreads();
    }
    // ---- attention over this graph's nodes ----
    for (int n = wid; n < NPG; n += 16) {
      float v = feat_s[n * 64 + lane] * xbuf[lane];
      for (int off = 32; off > 0; off >>= 1) v += __shfl_down(v, off);
      if (lane == 0) e_s[n] = v;
    }
    __syncthreads();
    if (tid < 64) {
      float mx = -1e30f;
      for (int n = lane; n < NPG; n += 64) mx = fmaxf(mx, e_s[n]);
      for (int off = 32; off > 0; off >>= 1) mx = fmaxf(mx, __shfl_down(mx, off));
      mx = __shfl(mx, 0);
      float ssum = 0.f;
      for (int n = lane; n < NPG; n += 64) {
        float ex = __expf(e_s[n] - mx);
        e_s[n] = ex;
        ssum += ex;
      }
      for (int off = 32; off > 0; off >>= 1) ssum += __shfl_down(ssum, off);
      if (lane == 0) scal[0] = ssum;
    }
    __syncthreads();
    float denom = scal[0];
    {
      float r = 0.f;
      for (int n = wid; n < NPG; n += 16) r += feat_s[n * 64 + lane] * e_s[n];
      red[wid][lane] = r;
    }
    __syncthreads();
    if (tid < 64) {
      float ro = 0.f;
#pragma unroll
      for (int ww = 0; ww < 16; ww++) ro += red[ww][lane];
      qstar[lane] = xbuf[lane];
      qstar[64 + lane] = ro / denom;
    }
    __syncthreads();
  }
  if (tid < 3) {
    float s = bp[tid];
    for (int k = 0; k < 128; k++) s += qstar[k] * Wp[tid * 128 + k];
    out[g * 3 + tid] = s;
  }
}

// ---------------- host ----------------

extern "C" void kernel_launch(void* const* d_in, const int* in_sizes, int n_in,
                              void* d_out, int out_size, void* d_ws, size_t ws_size,
                              hipStream_t stream) {
  const float* feats  = (const float*)d_in[0];
  const float* W_edge = (const float*)d_in[1];
  const float* b_edge = (const float*)d_in[2];
  const float* gWih   = (const float*)d_in[3];
  const float* gWhh   = (const float*)d_in[4];
  const float* gbih   = (const float*)d_in[5];
  const float* gbhh   = (const float*)d_in[6];
  const float* lWi0   = (const float*)d_in[7];
  const float* lWh0   = (const float*)d_in[8];
  const float* lbi0   = (const float*)d_in[9];
  const float* lbh0   = (const float*)d_in[10];
  const float* lWi1   = (const float*)d_in[11];
  const float* lWh1   = (const float*)d_in[12];
  const float* lbi1   = (const float*)d_in[13];
  const float* lbh1   = (const float*)d_in[14];
  const float* lWi2   = (const float*)d_in[15];
  const float* lWh2   = (const float*)d_in[16];
  const float* lbi2   = (const float*)d_in[17];
  const float* lbh2   = (const float*)d_in[18];
  const float* Wp     = (const float*)d_in[19];
  const float* bp     = (const float*)d_in[20];
  const int* src      = (const int*)d_in[21];
  const int* dst      = (const int*)d_in[22];
  const int* ety      = (const int*)d_in[23];
  float* out = (float*)d_out;

  char* ws = (char*)d_ws;
  u16* recs    = (u16*)ws;              // 2,048,000 B
  int* rows    = (int*)(ws + 2048000);  //   771,840 B (320 x 3 x 201)
  u16* WeTb    = (u16*)(ws + 2819840);  //    49,152 B
  u16* Wihb    = (u16*)(ws + 2868992);  //    24,576 B
  u16* Whhb    = (u16*)(ws + 2893568);  //    24,576 B
  u16* WTih0b  = (u16*)(ws + 2918144);  //    65,536 B
  u16* WThh0b  = (u16*)(ws + 2983680);  //    32,768 B
  u16* WTih1b  = (u16*)(ws + 3016448);  //    32,768 B
  u16* WThh1b  = (u16*)(ws + 3049216);  //    32,768 B
  u16* WTih2b  = (u16*)(ws + 3081984);  //    32,768 B
  u16* WThh2b  = (u16*)(ws + 3114752);  //    32,768 B

  k_csr<<<NGRAPH, 256, 0, stream>>>(src, dst, ety, recs, rows);
  k_prep<<<640, 256, 0, stream>>>(W_edge, gWih, gWhh, lWi0, lWh0, lWi1, lWh1, lWi2, lWh2,
                                  WeTb, Wihb, Whhb, WTih0b, WThh0b, WTih1b, WThh1b, WTih2b, WThh2b);
  k_ggnn<<<NGRAPH, NTHR, 0, stream>>>(feats, WeTb, b_edge, Wihb, Whhb, gbih, gbhh, recs, rows,
                                      WTih0b, WThh0b, WTih1b, WThh1b, WTih2b, WThh2b,
                                      lbi0, lbh0, lbi1, lbh1, lbi2, lbh2, Wp, bp, out);
}